// Round 14
// baseline (287.271 us; speedup 1.0000x reference)
//
#include <hip/hip_runtime.h>
#include <cmath>

#define N_IMG   8
#define PRE     1000
#define K_SEL   5000
#define NBIN    4096
#define TIE_CAP 4096
#define IMG_F   1344.0f
#define S_NEGINF 0x007FFFFFu
#define TILES   79             // ceil(5000/64)
#define GRPW    32000          // words per grp in lmat: 16 wblk x 1000 p x 2
#define CHUNK   8192           // elements per block in k_hist/k_compact

__constant__ int c_W[5]   = {336,168,84,42,21};
__constant__ int c_HW[5]  = {112896,28224,7056,1764,441};
__constant__ int c_OFF[5] = {0,338688,423360,444528,449820};

__device__ __forceinline__ unsigned f2s(float f){
  unsigned u = __float_as_uint(f);
  return (u & 0x80000000u) ? ~u : (u | 0x80000000u);
}
__device__ __forceinline__ float s2f(unsigned s){
  unsigned u = (s & 0x80000000u) ? (s & 0x7FFFFFFFu) : ~s;
  return __uint_as_float(u);
}
__device__ __forceinline__ const float* sel5(int l, const float* p0,const float* p1,const float* p2,const float* p3,const float* p4){
  switch(l){case 0:return p0;case 1:return p1;case 2:return p2;case 3:return p3;default:return p4;}
}

struct BoxV { float x1,y1,x2,y2; bool valid; };

// Bit-faithful torchvision BoxCoder.decode + clip + min-size validity.
__device__ BoxV decode_box(int lvl, int t, int n, const float* dl, const float* anchors){
  int HW = c_HW[lvl], W = c_W[lvl];
  int a = t % 3, pos = t / 3;          // t = (h*W+w)*3 + a
  int h = pos / W, w = pos - h*W;
  int g = c_OFF[lvl] + t;
  const float* an = anchors + (size_t)4*(size_t)g;
  float a0=an[0], a1=an[1], a2=an[2], a3=an[3];
  float aw = __fsub_rn(a2,a0), ah = __fsub_rn(a3,a1);
  float acx = __fadd_rn(a0, __fmul_rn(0.5f,aw));
  float acy = __fadd_rn(a1, __fmul_rn(0.5f,ah));
  const float* dp = dl + ((size_t)n*12 + (size_t)a*4)*(size_t)HW + (size_t)h*W + (size_t)w;
  float dx = dp[0], dy = dp[HW], dwv = dp[2*(size_t)HW], dhv = dp[3*(size_t)HW];
  const float CLAMP = (float)4.135166556742356;  // log(1000/16)
  dwv = fminf(dwv, CLAMP); dhv = fminf(dhv, CLAMP);
  float pcx = __fadd_rn(__fmul_rn(dx,aw), acx);
  float pcy = __fadd_rn(__fmul_rn(dy,ah), acy);
  float pw = __fmul_rn((float)::exp((double)dwv), aw);
  float ph = __fmul_rn((float)::exp((double)dhv), ah);
  float hx = __fmul_rn(0.5f,pw), hy = __fmul_rn(0.5f,ph);
  BoxV b;
  b.x1 = fminf(fmaxf(__fsub_rn(pcx,hx),0.0f),IMG_F);
  b.y1 = fminf(fmaxf(__fsub_rn(pcy,hy),0.0f),IMG_F);
  b.x2 = fminf(fmaxf(__fadd_rn(pcx,hx),0.0f),IMG_F);
  b.y2 = fminf(fmaxf(__fadd_rn(pcy,hy),0.0f),IMG_F);
  b.valid = (__fsub_rn(b.x2,b.x1) >= 1e-3f) && (__fsub_rn(b.y2,b.y1) >= 1e-3f);
  return b;
}

// key = (~s_eff)<<22 | lvl<<19 | t : ascending sort == (score desc, level asc, idx asc)
__device__ unsigned long long make_key(unsigned s, int lvl, int t, int n, const float* dl, const float* anchors){
  BoxV b = decode_box(lvl,t,n,dl,anchors);
  unsigned se = b.valid ? s : S_NEGINF;     // invalid -> skey = -inf
  return ((unsigned long long)(~se) << 22) | ((unsigned long long)(unsigned)lvl << 19) | (unsigned long long)(unsigned)t;
}

// ---------------- K1: per-(image,level) 12-bit score histogram (chunked grid) ----------------
__global__ __launch_bounds__(256) void k_hist(const float* o0,const float* o1,const float* o2,const float* o3,const float* o4,
                                              unsigned* hist){
  int grp = blockIdx.y; int n = grp/5, lvl = grp - n*5;
  int HW = c_HW[lvl], M = 3*HW;
  int base = blockIdx.x * CHUNK;
  if (base >= M) return;                 // idle block for short levels
  int end = min(base + CHUNK, M);
  const float* ob = sel5(lvl,o0,o1,o2,o3,o4) + (size_t)n*(size_t)M;
  __shared__ unsigned lh[NBIN];
  for (int b = threadIdx.x; b < NBIN; b += 256) lh[b] = 0;
  __syncthreads();
  for (int i = base + threadIdx.x; i < end; i += 256){
    unsigned s = f2s(ob[i]);
    atomicAdd(&lh[s >> 20], 1u);
  }
  __syncthreads();
  unsigned* gh = hist + (size_t)grp*NBIN;
  for (int b = threadIdx.x; b < NBIN; b += 256){ unsigned v = lh[b]; if (v) atomicAdd(&gh[b], v); }
}

// ---------------- K2: find bin containing the 1000th-largest score ----------------
__global__ __launch_bounds__(256) void k_scan(const unsigned* hist, unsigned* thi){
  int grp = blockIdx.x;
  const unsigned* gh = hist + (size_t)grp*NBIN;
  __shared__ unsigned part[256];
  unsigned ssum = 0;
  int base = threadIdx.x*16;
  for (int b = base; b < base+16; ++b) ssum += gh[b];
  part[threadIdx.x] = ssum;
  __syncthreads();
  if (threadIdx.x == 0){
    int k = PRE;
    int c = 255;
    while ((int)part[c] < k){ k -= (int)part[c]; --c; }
    int b = c*16 + 15;
    while ((int)gh[b] < k){ k -= (int)gh[b]; --b; }
    thi[grp] = (unsigned)b;
  }
}

// ---------------- K3: compact >bin elements (two-phase: LDS lists + block reservation) ----------------
__global__ __launch_bounds__(256) void k_compact(const float* o0,const float* o1,const float* o2,const float* o3,const float* o4,
                                                 const float* d0,const float* d1,const float* d2,const float* d3,const float* d4,
                                                 const float* anchors, const unsigned* thi,
                                                 unsigned* cnt_gt, unsigned* cnt_eq,
                                                 unsigned long long* cand, unsigned long long* keys){
  int grp = blockIdx.y; int n = grp/5, lvl = grp - n*5;
  int HW = c_HW[lvl], M = 3*HW;
  int base = blockIdx.x * CHUNK;
  if (base >= M) return;
  int end = min(base + CHUNK, M);
  const float* ob = sel5(lvl,o0,o1,o2,o3,o4) + (size_t)n*(size_t)M;
  const float* dl = sel5(lvl,d0,d1,d2,d3,d4);
  unsigned T = thi[grp];
  __shared__ int lgt[1024];              // per-group gt total < 1000 -> block gt <= 999
  __shared__ int leq[TIE_CAP];
  __shared__ unsigned cgt_s, ceq_s, bgt_s, beq_s;
  if (threadIdx.x == 0){ cgt_s = 0u; ceq_s = 0u; }
  __syncthreads();
  for (int i = base + threadIdx.x; i < end; i += 256){
    unsigned s = f2s(ob[i]);
    unsigned sh = s >> 20;
    if (sh > T){
      unsigned k = atomicAdd(&cgt_s, 1u);
      if (k < 1024u) lgt[k] = i;
    } else if (sh == T){
      unsigned k = atomicAdd(&ceq_s, 1u);
      if (k < (unsigned)TIE_CAP) leq[k] = i;
    }
  }
  __syncthreads();
  if (threadIdx.x == 0){
    bgt_s = atomicAdd(&cnt_gt[grp], min(cgt_s, 1024u));
    beq_s = atomicAdd(&cnt_eq[grp], min(ceq_s, (unsigned)TIE_CAP));
  }
  __syncthreads();
  unsigned cg = min(cgt_s, 1024u), ce = min(ceq_s, (unsigned)TIE_CAP);
  unsigned bgt = bgt_s, beq = beq_s;
  unsigned long long* kout = keys + (size_t)n*K_SEL + (size_t)lvl*PRE;
  for (unsigned k = threadIdx.x; k < cg; k += 256){
    int i = lgt[k];
    unsigned s = f2s(ob[i]);
    int a = i / HW; int rem = i - a*HW; int t = rem*3 + a;
    kout[bgt + k] = make_key(s, lvl, t, n, dl, anchors);
  }
  for (unsigned k = threadIdx.x; k < ce; k += 256){
    unsigned e = beq + k;
    if (e < (unsigned)TIE_CAP){
      int i = leq[k];
      unsigned s = f2s(ob[i]);
      int a = i / HW; int rem = i - a*HW; int t = rem*3 + a;
      cand[(size_t)grp*TIE_CAP + e] = ((unsigned long long)(~s) << 19) | (unsigned long long)(unsigned)t;
    }
  }
}

template<int SZ>
__device__ void bitonic(unsigned long long* sk){
  for (int k = 2; k <= SZ; k <<= 1){
    for (int j = k >> 1; j > 0; j >>= 1){
      for (int i = threadIdx.x; i < SZ; i += blockDim.x){
        int ix = i ^ j;
        if (ix > i){
          unsigned long long va = sk[i], vb = sk[ix];
          if ((va > vb) == ((i & k) == 0)){ sk[i] = vb; sk[ix] = va; }
        }
      }
      __syncthreads();
    }
  }
}

// ---------------- K4: exact boundary selection via rank-select (no sort, no barriers) ----------------
// Tie-bin keys are unique (anchor idx in low bits) -> rank = #{keys smaller} is an exact
// permutation. Candidate with rank < need lands at kout[rank] == j-th smallest == the
// bitonic result, bit-for-bit. Broadcast LDS reads, pipelined; replaces 55 barrier passes.
__global__ __launch_bounds__(256) void k_tiesel(const float* d0,const float* d1,const float* d2,const float* d3,const float* d4,
                                                const float* anchors,
                                                const unsigned* cnt_gt, const unsigned* cnt_eq,
                                                const unsigned long long* cand, unsigned long long* keys){
  int grp = blockIdx.x; int n = grp/5, lvl = grp - n*5;
  __shared__ unsigned long long sk[TIE_CAP];
  int ne = min((int)cnt_eq[grp], TIE_CAP);
  for (int i = threadIdx.x; i < ne; i += 256)
    sk[i] = cand[(size_t)grp*TIE_CAP + i];
  __syncthreads();
  int cg = (int)cnt_gt[grp];
  int need = PRE - cg;
  const float* dl = sel5(lvl,d0,d1,d2,d3,d4);
  unsigned long long* kout = keys + (size_t)n*K_SEL + (size_t)lvl*PRE + cg;
  // pathological overflow pad (ne < need): harmless invalid keys
  for (int j = ne + threadIdx.x; j < need; j += 256)
    kout[j] = ((unsigned long long)(~S_NEGINF) << 22);
  for (int c = threadIdx.x; c < ne; c += 256){
    unsigned long long ck = sk[c];
    int rank = 0;
    int i = 0;
    for (; i + 8 <= ne; i += 8){
      rank += (int)(sk[i  ] < ck) + (int)(sk[i+1] < ck)
            + (int)(sk[i+2] < ck) + (int)(sk[i+3] < ck)
            + (int)(sk[i+4] < ck) + (int)(sk[i+5] < ck)
            + (int)(sk[i+6] < ck) + (int)(sk[i+7] < ck);
    }
    for (; i < ne; ++i) rank += (int)(sk[i] < ck);
    if (rank < need){
      unsigned t = (unsigned)(ck & 0x7FFFFu);
      unsigned s = ~((unsigned)(ck >> 19));
      kout[rank] = make_key(s, lvl, (int)t, n, dl, anchors);
    }
  }
}

// ---------------- K5a: sort each (image,level) run; decode level-space arrays ----------------
__global__ __launch_bounds__(256) void k_sortlvl(unsigned long long* keys,
                                                 const float* d0,const float* d1,const float* d2,const float* d3,const float* d4,
                                                 const float* anchors,
                                                 float4* lbox, float4* lobox, float* loarea, float* lskey){
  int grp = blockIdx.x; int n = grp/5, lvl = grp - n*5;
  __shared__ unsigned long long sk[1024];
  unsigned long long* kp = keys + (size_t)n*K_SEL + (size_t)lvl*PRE;
  for (int i = threadIdx.x; i < 1024; i += 256)
    sk[i] = (i < PRE) ? kp[i] : ~0ULL;
  __syncthreads();
  bitonic<1024>(sk);
  const float* dl = sel5(lvl,d0,d1,d2,d3,d4);
  for (int i = threadIdx.x; i < PRE; i += 256){
    unsigned long long key = sk[i];
    kp[i] = key;                          // sorted run back to global (k_rank reads it)
    int t = (int)(key & 0x7FFFFu);
    unsigned se = ~((unsigned)(key >> 22));
    BoxV b = decode_box(lvl, t, n, dl, anchors);
    size_t o = (size_t)grp*PRE + i;
    lbox[o] = make_float4(b.x1,b.y1,b.x2,b.y2);
    lskey[o] = s2f(se);                   // -inf if invalid
    float off = (float)lvl * 1345.0f;     // (IMG+1) batched-NMS offset
    float ox1 = __fadd_rn(b.x1, off), oy1 = __fadd_rn(b.y1, off);
    float ox2 = __fadd_rn(b.x2, off), oy2 = __fadd_rn(b.y2, off);
    lobox[o] = make_float4(ox1,oy1,ox2,oy2);
    loarea[o] = __fmul_rn(__fsub_rn(ox2,ox1), __fsub_rn(oy2,oy1));
  }
}

// ---------------- K5b: global rank of each level element (keys globally unique) ----------------
// rankinfo[rank] = p | (lvl<<10) | (valid<<13)
__global__ __launch_bounds__(256) void k_rank(const unsigned long long* keys, unsigned* rankinfo){
  int grp = blockIdx.x; int n = grp/5, lvl = grp - n*5;
  __shared__ unsigned long long sl[K_SEL];
  for (int i = threadIdx.x; i < K_SEL; i += 256) sl[i] = keys[(size_t)n*K_SEL + i];
  __syncthreads();
  for (int j = threadIdx.x; j < PRE; j += 256){
    unsigned long long k = sl[lvl*PRE + j];
    int rank = j;
    #pragma unroll
    for (int m = 0; m < 5; ++m){
      if (m == lvl) continue;
      const unsigned long long* s = sl + m*PRE;
      int lo = 0, hi = PRE;
      while (lo < hi){ int mid = (lo+hi) >> 1; if (s[mid] < k) lo = mid+1; else hi = mid; }
      rank += lo;
    }
    unsigned se = ~((unsigned)(k >> 22));
    unsigned info = (unsigned)j | ((unsigned)lvl << 10) | ((se != S_NEGINF) ? (1u<<13) : 0u);
    rankinfo[(size_t)n*K_SEL + rank] = info;   // exact permutation of [0,5000)
  }
}

// ---------------- K6a: suppression bit-matrix, ballot + column layout, 4 waves/block ----------------
__global__ __launch_bounds__(256) void k_ioumat_lvl(const float4* lobox, const float* loarea, unsigned* lmat){
  int grp = blockIdx.y;                  // n*5 + L
  int wblk = blockIdx.x;                 // j-block: j = wblk*64 + lane
  int tid = threadIdx.x;
  int lane = tid & 63, q = tid >> 6;
  __shared__ float sx1[PRE], sy1[PRE], sx2[PRE], sy2[PRE], sar[PRE];
  for (int i = tid; i < PRE; i += 256){
    float4 bb = lobox[(size_t)grp*PRE + i];
    sx1[i]=bb.x; sy1[i]=bb.y; sx2[i]=bb.z; sy2[i]=bb.w;
    sar[i]=loarea[(size_t)grp*PRE + i];
  }
  __syncthreads();
  int j = wblk*64 + lane;
  float jx1=0.f,jy1=0.f,jx2=0.f,jy2=0.f,ja=0.f;
  if (j < PRE){
    float4 bb = lobox[(size_t)grp*PRE + j];
    jx1=bb.x; jy1=bb.y; jx2=bb.z; jy2=bb.w; ja=loarea[(size_t)grp*PRE + j];
  }
  unsigned* mg = lmat + (size_t)grp*GRPW + (size_t)wblk*2*PRE;
  int pmax = min(PRE, wblk*64 + 63);     // rows p >= pmax: no j>p in this block
  int q0 = q*250, q1 = q0 + 250;
  int pm = min(q1, pmax);

#define IOU_HIT(P, OUT) { \
    float bx1=sx1[P], by1=sy1[P], bx2=sx2[P], by2=sy2[P], ba=sar[P]; \
    float ltx = fmaxf(bx1, jx1), lty = fmaxf(by1, jy1); \
    float rbx = fminf(bx2, jx2), rby = fminf(by2, jy2); \
    float ww = fmaxf(__fsub_rn(rbx,ltx), 0.0f); \
    float hh = fmaxf(__fsub_rn(rby,lty), 0.0f); \
    float inter = __fmul_rn(ww,hh); \
    float uni = __fsub_rn(__fadd_rn(ba, ja), inter); \
    OUT = (__fdiv_rn(inter,uni) > 0.7f) && (j > (P)) && (j < PRE); }

  int p = q0;
  for (; p + 4 <= pm; p += 4){
    bool h0,h1,h2,h3;
    IOU_HIT(p,   h0);
    IOU_HIT(p+1, h1);
    IOU_HIT(p+2, h2);
    IOU_HIT(p+3, h3);
    unsigned long long b0 = __ballot(h0), b1 = __ballot(h1);
    unsigned long long b2 = __ballot(h2), b3 = __ballot(h3);
    if ((lane & 31) == 0){
      int d = lane >> 5;
      mg[(p  )*2 + d] = (lane==0) ? (unsigned)b0 : (unsigned)(b0>>32);
      mg[(p+1)*2 + d] = (lane==0) ? (unsigned)b1 : (unsigned)(b1>>32);
      mg[(p+2)*2 + d] = (lane==0) ? (unsigned)b2 : (unsigned)(b2>>32);
      mg[(p+3)*2 + d] = (lane==0) ? (unsigned)b3 : (unsigned)(b3>>32);
    }
  }
  for (; p < pm; ++p){
    bool h; IOU_HIT(p, h);
    unsigned long long bal = __ballot(h);
    if ((lane & 31) == 0)
      mg[p*2 + (lane>>5)] = (lane==0) ? (unsigned)bal : (unsigned)(bal>>32);
  }
#undef IOU_HIT
  int zs = (pm > q0 ? pm : q0);
  for (int w = zs*2 + lane; w < q1*2; w += 64) mg[w] = 0u;   // contiguous zero-fill
}

// ---------------- K6b: tile-parallel greedy scan, latency-batched TPROC ----------------
__global__ __launch_bounds__(64) void k_scan_nms5(const unsigned* rankinfo, const unsigned* lmat,
                                                  const float4* lbox, const float* lskey, float* out){
  __shared__ unsigned lrows[64][36];     // row-major tile; stride 36 words
  __shared__ unsigned lsup[160];         // 5 levels x 32 words suppression state
  int n = blockIdx.x; int lane = threadIdx.x;
  int n5 = n*5;
  const unsigned* rin = rankinfo + (size_t)n*K_SEL;
  float* outn = out + (size_t)n*PRE*5;
  for (int i = lane; i < 160; i += 64) lsup[i] = 0u;
  int kept_total = 0;
  uint2 Pa,Pb,Pc,Pd,Pe,Pf,Pg,Ph,Pi,Pj,Pk,Pl,Pm,Pn,Po,Pp;  // 16x8B staging
  float4 boxP; float scP = 0.f;
  unsigned infoC, infoN;
  int rgrp = lane >> 4;                  // 0..3: row subgroup
  unsigned wboff = (unsigned)(lane & 15) * (2u*PRE);  // my wblk's column segment
  int wb2 = (lane & 15) << 1;            // word index within row

#define SLOAD(INFO) { \
    unsigned L_ = ((INFO)>>10)&7u; unsigned p_ = (INFO) & 1023u; \
    unsigned rowu_ = ((unsigned)n5 + L_)*GRPW + p_*2u; \
    unsigned rb_; \
    rb_ = __shfl(rowu_,  0 + rgrp); Pa = *(const uint2*)(lmat + rb_ + wboff); \
    rb_ = __shfl(rowu_,  4 + rgrp); Pb = *(const uint2*)(lmat + rb_ + wboff); \
    rb_ = __shfl(rowu_,  8 + rgrp); Pc = *(const uint2*)(lmat + rb_ + wboff); \
    rb_ = __shfl(rowu_, 12 + rgrp); Pd = *(const uint2*)(lmat + rb_ + wboff); \
    rb_ = __shfl(rowu_, 16 + rgrp); Pe = *(const uint2*)(lmat + rb_ + wboff); \
    rb_ = __shfl(rowu_, 20 + rgrp); Pf = *(const uint2*)(lmat + rb_ + wboff); \
    rb_ = __shfl(rowu_, 24 + rgrp); Pg = *(const uint2*)(lmat + rb_ + wboff); \
    rb_ = __shfl(rowu_, 28 + rgrp); Ph = *(const uint2*)(lmat + rb_ + wboff); \
    rb_ = __shfl(rowu_, 32 + rgrp); Pi = *(const uint2*)(lmat + rb_ + wboff); \
    rb_ = __shfl(rowu_, 36 + rgrp); Pj = *(const uint2*)(lmat + rb_ + wboff); \
    rb_ = __shfl(rowu_, 40 + rgrp); Pk = *(const uint2*)(lmat + rb_ + wboff); \
    rb_ = __shfl(rowu_, 44 + rgrp); Pl = *(const uint2*)(lmat + rb_ + wboff); \
    rb_ = __shfl(rowu_, 48 + rgrp); Pm = *(const uint2*)(lmat + rb_ + wboff); \
    rb_ = __shfl(rowu_, 52 + rgrp); Pn = *(const uint2*)(lmat + rb_ + wboff); \
    rb_ = __shfl(rowu_, 56 + rgrp); Po = *(const uint2*)(lmat + rb_ + wboff); \
    rb_ = __shfl(rowu_, 60 + rgrp); Pp = *(const uint2*)(lmat + rb_ + wboff); \
    size_t bi_ = (size_t)((unsigned)n5 + L_)*PRE + p_; \
    boxP = lbox[bi_]; scP = lskey[bi_]; }

#define SWRITE() { \
    *(uint2*)&lrows[ 0 + rgrp][wb2] = Pa; *(uint2*)&lrows[ 4 + rgrp][wb2] = Pb; \
    *(uint2*)&lrows[ 8 + rgrp][wb2] = Pc; *(uint2*)&lrows[12 + rgrp][wb2] = Pd; \
    *(uint2*)&lrows[16 + rgrp][wb2] = Pe; *(uint2*)&lrows[20 + rgrp][wb2] = Pf; \
    *(uint2*)&lrows[24 + rgrp][wb2] = Pg; *(uint2*)&lrows[28 + rgrp][wb2] = Ph; \
    *(uint2*)&lrows[32 + rgrp][wb2] = Pi; *(uint2*)&lrows[36 + rgrp][wb2] = Pj; \
    *(uint2*)&lrows[40 + rgrp][wb2] = Pk; *(uint2*)&lrows[44 + rgrp][wb2] = Pl; \
    *(uint2*)&lrows[48 + rgrp][wb2] = Pm; *(uint2*)&lrows[52 + rgrp][wb2] = Pn; \
    *(uint2*)&lrows[56 + rgrp][wb2] = Po; *(uint2*)&lrows[60 + rgrp][wb2] = Pp; }

#define GRP16(B, ACC, SH) { \
    unsigned q0_=lrows[(B)+ 0][idxw_], q1_=lrows[(B)+ 1][idxw_], \
             q2_=lrows[(B)+ 2][idxw_], q3_=lrows[(B)+ 3][idxw_], \
             q4_=lrows[(B)+ 4][idxw_], q5_=lrows[(B)+ 5][idxw_], \
             q6_=lrows[(B)+ 6][idxw_], q7_=lrows[(B)+ 7][idxw_], \
             q8_=lrows[(B)+ 8][idxw_], q9_=lrows[(B)+ 9][idxw_], \
             qa_=lrows[(B)+10][idxw_], qb_=lrows[(B)+11][idxw_], \
             qc_=lrows[(B)+12][idxw_], qd_=lrows[(B)+13][idxw_], \
             qe_=lrows[(B)+14][idxw_], qf_=lrows[(B)+15][idxw_]; \
    ACC |= (((q0_>>pb_)&1u)<<((SH)+ 0)) | (((q1_>>pb_)&1u)<<((SH)+ 1)) \
         | (((q2_>>pb_)&1u)<<((SH)+ 2)) | (((q3_>>pb_)&1u)<<((SH)+ 3)) \
         | (((q4_>>pb_)&1u)<<((SH)+ 4)) | (((q5_>>pb_)&1u)<<((SH)+ 5)) \
         | (((q6_>>pb_)&1u)<<((SH)+ 6)) | (((q7_>>pb_)&1u)<<((SH)+ 7)) \
         | (((q8_>>pb_)&1u)<<((SH)+ 8)) | (((q9_>>pb_)&1u)<<((SH)+ 9)) \
         | (((qa_>>pb_)&1u)<<((SH)+10)) | (((qb_>>pb_)&1u)<<((SH)+11)) \
         | (((qc_>>pb_)&1u)<<((SH)+12)) | (((qd_>>pb_)&1u)<<((SH)+13)) \
         | (((qe_>>pb_)&1u)<<((SH)+14)) | (((qf_>>pb_)&1u)<<((SH)+15)); }

#define TPROC(INFO, BOX, SC, baseexpr) { \
    int base_ = (baseexpr); \
    unsigned L_ = ((INFO)>>10)&7u; unsigned p_ = (INFO) & 1023u; \
    int idxw_ = (int)(p_ >> 5); unsigned pb_ = p_ & 31u; \
    unsigned long long lb0_=__ballot(L_==0u), lb1_=__ballot(L_==1u), \
                       lb2_=__ballot(L_==2u), lb3_=__ballot(L_==3u), lb4_=__ballot(L_==4u); \
    unsigned long long myLvl_ = (L_==0u)?lb0_:(L_==1u)?lb1_:(L_==2u)?lb2_:(L_==3u)?lb3_:lb4_; \
    unsigned sw_ = lsup[L_*32u + (unsigned)idxw_]; \
    bool ok_ = ((((INFO)>>13)&1u)!=0u) && (base_ + lane < K_SEL) && (((sw_>>pb_)&1u)==0u); \
    unsigned long long cand_ = __ballot(ok_); \
    unsigned alo_ = 0u, ahi_ = 0u; \
    GRP16( 0, alo_,  0); GRP16(16, alo_, 16); \
    GRP16(32, ahi_,  0); GRP16(48, ahi_, 16); \
    unsigned long long cm_ = ((((unsigned long long)ahi_)<<32)|(unsigned long long)alo_) & myLvl_; \
    unsigned long long keptM_ = 0ull; \
    while (cand_){ \
      bool safe_ = (((cand_>>lane)&1ull)!=0ull) && ((cm_ & cand_)==0ull); \
      unsigned long long nk_ = __ballot(safe_); \
      keptM_ |= nk_; \
      bool dead_ = (((cand_>>lane)&1ull)!=0ull) && ((cm_ & nk_)!=0ull); \
      cand_ &= ~(nk_ | __ballot(dead_)); \
    } \
    if (((keptM_>>lane)&1ull)!=0ull){ \
      unsigned sb_ = L_*32u; \
      _Pragma("unroll") \
      for (int k_ = 0; k_ < 32; ++k_){ \
        unsigned w_ = (unsigned)((k_+lane)&31); \
        atomicOr(&lsup[sb_+w_], lrows[lane][w_]); \
      } \
    } \
    int pos_ = kept_total + (int)__popcll(keptM_ & ((1ull<<lane)-1ull)); \
    if ((((keptM_>>lane)&1ull)!=0ull) && pos_ < PRE){ \
      float* orow_ = outn + (size_t)pos_*5; \
      orow_[0]=(BOX).x; orow_[1]=(BOX).y; orow_[2]=(BOX).z; orow_[3]=(BOX).w; orow_[4]=(SC); \
    } \
    kept_total += (int)__popcll(keptM_); \
    asm volatile("s_waitcnt lgkmcnt(0)" ::: "memory"); \
  }

  infoC = rin[lane];
  SLOAD(infoC);                          // tile 0 rows -> regs, box -> boxP
  SWRITE();                              // tile 0 rows -> LDS
  float4 boxC = boxP; float scC = scP;
  infoN = rin[64 + lane];

  for (int t = 0; t < TILES; ++t){
    if (t+1 < TILES) SLOAD(infoN);       // issue next tile's loads (rows + box)
    asm volatile("s_waitcnt lgkmcnt(0)" ::: "memory");   // lrows writes visible
    TPROC(infoC, boxC, scC, t*64);
    if (kept_total >= PRE) break;
    if (t+1 < TILES){
      SWRITE();                          // waits next tile's loads (covered by TPROC)
      boxC = boxP; scC = scP;
      infoC = infoN;
      if (t+2 < TILES){
        int nx = (t+2)*64 + lane; if (nx > K_SEL-1) nx = K_SEL-1;
        infoN = rin[nx];
      }
    }
  }
#undef SLOAD
#undef SWRITE
#undef GRP16
#undef TPROC
}

// ---------------- fallback path (ws too small): round-3 kernels ----------------
__global__ __launch_bounds__(256) void k_sortimg(const unsigned long long* keys,
                                                 const float* d0,const float* d1,const float* d2,const float* d3,const float* d4,
                                                 const float* anchors,
                                                 float4* sbox, float* sskey, int* slvl){
  int n = blockIdx.x;
  __shared__ unsigned long long sk[8192];
  for (int i = threadIdx.x; i < 8192; i += 256)
    sk[i] = (i < K_SEL) ? keys[(size_t)n*K_SEL + i] : ~0ULL;
  __syncthreads();
  bitonic<8192>(sk);
  for (int r = threadIdx.x; r < K_SEL; r += 256){
    unsigned long long key = sk[r];
    int t = (int)(key & 0x7FFFFu);
    int lvl = (int)((key >> 19) & 7u);
    unsigned se = ~((unsigned)(key >> 22));
    const float* dl = sel5(lvl,d0,d1,d2,d3,d4);
    BoxV b = decode_box(lvl, t, n, dl, anchors);
    sbox[(size_t)n*K_SEL + r] = make_float4(b.x1,b.y1,b.x2,b.y2);
    sskey[(size_t)n*K_SEL + r] = s2f(se);
    slvl[(size_t)n*K_SEL + r] = lvl;
  }
}

__global__ __launch_bounds__(256) void k_nms(const float4* sbox, const float* sskey, const int* slvl, float* out){
  int n = blockIdx.x, tid = threadIdx.x;
  __shared__ float kx1[PRE], ky1[PRE], kx2[PRE], ky2[PRE], kar[PRE];
  __shared__ int klv[PRE];
  __shared__ int nv_s, flag_s;
  for (int i = tid; i < PRE*5; i += 256) out[(size_t)n*PRE*5 + i] = 0.0f;
  if (tid == 0){ nv_s = 0; flag_s = 0; }
  __syncthreads();
  int c = 0;
  for (int i = tid; i < K_SEL; i += 256)
    if (sskey[(size_t)n*K_SEL + i] != -INFINITY) ++c;
  atomicAdd(&nv_s, c);
  __syncthreads();
  int nvalid = nv_s;
  int kept = 0;
  for (int i = 0; i < nvalid; ++i){
    float4 b = sbox[(size_t)n*K_SEL + i];
    int lv = slvl[(size_t)n*K_SEL + i];
    float off = (float)lv * 1345.0f;
    float ox1 = __fadd_rn(b.x, off), oy1 = __fadd_rn(b.y, off);
    float ox2 = __fadd_rn(b.z, off), oy2 = __fadd_rn(b.w, off);
    float area = __fmul_rn(__fsub_rn(ox2,ox1), __fsub_rn(oy2,oy1));
    bool hit = false;
    for (int j = tid; j < kept; j += 256){
      if (klv[j] == lv){
        float ltx = fmaxf(kx1[j], ox1), lty = fmaxf(ky1[j], oy1);
        float rbx = fminf(kx2[j], ox2), rby = fminf(ky2[j], oy2);
        float w = fmaxf(__fsub_rn(rbx,ltx), 0.0f);
        float h = fmaxf(__fsub_rn(rby,lty), 0.0f);
        float inter = __fmul_rn(w,h);
        float uni = __fsub_rn(__fadd_rn(kar[j], area), inter);
        if (__fdiv_rn(inter,uni) > 0.7f) hit = true;
      }
    }
    if (hit) flag_s = 1;
    __syncthreads();
    int sup = flag_s;
    __syncthreads();
    if (!sup){
      if (tid == 0){
        kx1[kept]=ox1; ky1[kept]=oy1; kx2[kept]=ox2; ky2[kept]=oy2; kar[kept]=area; klv[kept]=lv;
        float* orow = out + (size_t)n*PRE*5 + (size_t)kept*5;
        orow[0]=b.x; orow[1]=b.y; orow[2]=b.z; orow[3]=b.w;
        orow[4]=sskey[(size_t)n*K_SEL + i];
      }
      ++kept;
    }
    if (tid == 0) flag_s = 0;
    __syncthreads();
    if (kept == PRE) break;
  }
}

extern "C" void kernel_launch(void* const* d_in, const int* in_sizes, int n_in,
                              void* d_out, int out_size, void* d_ws, size_t ws_size,
                              hipStream_t stream) {
  bool interleaved = (in_sizes[1] == 4*in_sizes[0]);
  const float* obj[5]; const float* dlt[5];
  for (int i = 0; i < 5; ++i){
    if (interleaved){ obj[i] = (const float*)d_in[2*i]; dlt[i] = (const float*)d_in[2*i+1]; }
    else            { obj[i] = (const float*)d_in[i];   dlt[i] = (const float*)d_in[5+i]; }
  }
  const float* anchors = (const float*)d_in[10];

  char* ws = (char*)d_ws;
  unsigned* hist            = (unsigned*)(ws);                     // 655360
  unsigned* cnt_gt          = (unsigned*)(ws + 655360);            // 160
  unsigned* cnt_eq          = (unsigned*)(ws + 655520);            // 160
  unsigned* thi             = (unsigned*)(ws + 655680);            // 160 -> counters end 655840
  unsigned long long* cand  = (unsigned long long*)(ws + 655840);  // 1310720 -> 1966560
  unsigned long long* keys  = (unsigned long long*)(ws + 1966560); // 320000 -> 2286560
  float4* lbox              = (float4*)(ws + 2286560);             // 640000 -> 2926560
  float4* lobox             = (float4*)(ws + 2926560);             // 640000 -> 3566560
  float* loarea             = (float*)(ws + 3566560);              // 160000 -> 3726560
  float* lskey              = (float*)(ws + 3726560);              // 160000 -> 3886560
  unsigned* rankinfo        = (unsigned*)(ws + 3886560);           // 160000 -> 4046560
  unsigned* lmat            = (unsigned*)(ws + 4046560);           // 5120000 -> 9166560
  float4* sbox              = (float4*)(ws + 9166560);             // fallback: 640000 -> 9806560
  float* sskey              = (float*)(ws + 9806560);              // 160000 -> 9966560
  int* slvl                 = (int*)(ws + 9966560);                // 160000 -> 10126560
  const size_t NEED = 10126560;

  hipMemsetAsync(ws, 0, 655840, stream);   // hist + counters

  dim3 gChunk(42, 40);                   // 42 chunks x 8192 covers level-0's 338688
  k_hist<<<gChunk, 256, 0, stream>>>(obj[0],obj[1],obj[2],obj[3],obj[4], hist);
  k_scan<<<40, 256, 0, stream>>>(hist, thi);
  k_compact<<<gChunk, 256, 0, stream>>>(obj[0],obj[1],obj[2],obj[3],obj[4],
                                        dlt[0],dlt[1],dlt[2],dlt[3],dlt[4],
                                        anchors, thi, cnt_gt, cnt_eq, cand, keys);
  k_tiesel<<<40, 256, 0, stream>>>(dlt[0],dlt[1],dlt[2],dlt[3],dlt[4], anchors,
                                   cnt_gt, cnt_eq, cand, keys);
  if (ws_size >= NEED){
    k_sortlvl<<<40, 256, 0, stream>>>(keys, dlt[0],dlt[1],dlt[2],dlt[3],dlt[4], anchors,
                                      lbox, lobox, loarea, lskey);
    k_rank<<<40, 256, 0, stream>>>(keys, rankinfo);
    k_ioumat_lvl<<<dim3(16, 40), 256, 0, stream>>>(lobox, loarea, lmat);
    hipMemsetAsync(d_out, 0, (size_t)out_size*sizeof(float), stream);
    k_scan_nms5<<<8, 64, 0, stream>>>(rankinfo, lmat, lbox, lskey, (float*)d_out);
  } else {
    k_sortimg<<<8, 256, 0, stream>>>(keys, dlt[0],dlt[1],dlt[2],dlt[3],dlt[4], anchors,
                                     sbox, sskey, slvl);
    k_nms<<<8, 256, 0, stream>>>(sbox, sskey, slvl, (float*)d_out);
  }
}

// Round 15
// 269.251 us; speedup vs baseline: 1.0669x; 1.0669x over previous
//
#include <hip/hip_runtime.h>
#include <cmath>

#define N_IMG   8
#define PRE     1000
#define K_SEL   5000
#define NBIN    4096
#define TIE_CAP 4096
#define IMG_F   1344.0f
#define S_NEGINF 0x007FFFFFu
#define TILES   79             // ceil(5000/64)
#define GRPW    32000          // words per grp in lmat: 16 wblk x 1000 p x 2
#define CHUNK   8192           // elements per block in k_hist/k_compact

__constant__ int c_W[5]   = {336,168,84,42,21};
__constant__ int c_HW[5]  = {112896,28224,7056,1764,441};
__constant__ int c_OFF[5] = {0,338688,423360,444528,449820};

__device__ __forceinline__ unsigned f2s(float f){
  unsigned u = __float_as_uint(f);
  return (u & 0x80000000u) ? ~u : (u | 0x80000000u);
}
__device__ __forceinline__ float s2f(unsigned s){
  unsigned u = (s & 0x80000000u) ? (s & 0x7FFFFFFFu) : ~s;
  return __uint_as_float(u);
}
__device__ __forceinline__ const float* sel5(int l, const float* p0,const float* p1,const float* p2,const float* p3,const float* p4){
  switch(l){case 0:return p0;case 1:return p1;case 2:return p2;case 3:return p3;default:return p4;}
}

struct BoxV { float x1,y1,x2,y2; bool valid; };

// Bit-faithful torchvision BoxCoder.decode + clip + min-size validity.
__device__ BoxV decode_box(int lvl, int t, int n, const float* dl, const float* anchors){
  int HW = c_HW[lvl], W = c_W[lvl];
  int a = t % 3, pos = t / 3;          // t = (h*W+w)*3 + a
  int h = pos / W, w = pos - h*W;
  int g = c_OFF[lvl] + t;
  const float* an = anchors + (size_t)4*(size_t)g;
  float a0=an[0], a1=an[1], a2=an[2], a3=an[3];
  float aw = __fsub_rn(a2,a0), ah = __fsub_rn(a3,a1);
  float acx = __fadd_rn(a0, __fmul_rn(0.5f,aw));
  float acy = __fadd_rn(a1, __fmul_rn(0.5f,ah));
  const float* dp = dl + ((size_t)n*12 + (size_t)a*4)*(size_t)HW + (size_t)h*W + (size_t)w;
  float dx = dp[0], dy = dp[HW], dwv = dp[2*(size_t)HW], dhv = dp[3*(size_t)HW];
  const float CLAMP = (float)4.135166556742356;  // log(1000/16)
  dwv = fminf(dwv, CLAMP); dhv = fminf(dhv, CLAMP);
  float pcx = __fadd_rn(__fmul_rn(dx,aw), acx);
  float pcy = __fadd_rn(__fmul_rn(dy,ah), acy);
  float pw = __fmul_rn((float)::exp((double)dwv), aw);
  float ph = __fmul_rn((float)::exp((double)dhv), ah);
  float hx = __fmul_rn(0.5f,pw), hy = __fmul_rn(0.5f,ph);
  BoxV b;
  b.x1 = fminf(fmaxf(__fsub_rn(pcx,hx),0.0f),IMG_F);
  b.y1 = fminf(fmaxf(__fsub_rn(pcy,hy),0.0f),IMG_F);
  b.x2 = fminf(fmaxf(__fadd_rn(pcx,hx),0.0f),IMG_F);
  b.y2 = fminf(fmaxf(__fadd_rn(pcy,hy),0.0f),IMG_F);
  b.valid = (__fsub_rn(b.x2,b.x1) >= 1e-3f) && (__fsub_rn(b.y2,b.y1) >= 1e-3f);
  return b;
}

// key = (~s_eff)<<22 | lvl<<19 | t : ascending sort == (score desc, level asc, idx asc)
__device__ unsigned long long make_key(unsigned s, int lvl, int t, int n, const float* dl, const float* anchors){
  BoxV b = decode_box(lvl,t,n,dl,anchors);
  unsigned se = b.valid ? s : S_NEGINF;     // invalid -> skey = -inf
  return ((unsigned long long)(~se) << 22) | ((unsigned long long)(unsigned)lvl << 19) | (unsigned long long)(unsigned)t;
}

// ---------------- K1: per-(image,level) 12-bit score histogram (chunked grid) ----------------
__global__ __launch_bounds__(256) void k_hist(const float* o0,const float* o1,const float* o2,const float* o3,const float* o4,
                                              unsigned* hist){
  int grp = blockIdx.y; int n = grp/5, lvl = grp - n*5;
  int HW = c_HW[lvl], M = 3*HW;
  int base = blockIdx.x * CHUNK;
  if (base >= M) return;                 // idle block for short levels
  int end = min(base + CHUNK, M);
  const float* ob = sel5(lvl,o0,o1,o2,o3,o4) + (size_t)n*(size_t)M;
  __shared__ unsigned lh[NBIN];
  for (int b = threadIdx.x; b < NBIN; b += 256) lh[b] = 0;
  __syncthreads();
  for (int i = base + threadIdx.x; i < end; i += 256){
    unsigned s = f2s(ob[i]);
    atomicAdd(&lh[s >> 20], 1u);
  }
  __syncthreads();
  unsigned* gh = hist + (size_t)grp*NBIN;
  for (int b = threadIdx.x; b < NBIN; b += 256){ unsigned v = lh[b]; if (v) atomicAdd(&gh[b], v); }
}

// ---------------- K2: find bin containing the 1000th-largest score ----------------
__global__ __launch_bounds__(256) void k_scan(const unsigned* hist, unsigned* thi){
  int grp = blockIdx.x;
  const unsigned* gh = hist + (size_t)grp*NBIN;
  __shared__ unsigned part[256];
  unsigned ssum = 0;
  int base = threadIdx.x*16;
  for (int b = base; b < base+16; ++b) ssum += gh[b];
  part[threadIdx.x] = ssum;
  __syncthreads();
  if (threadIdx.x == 0){
    int k = PRE;
    int c = 255;
    while ((int)part[c] < k){ k -= (int)part[c]; --c; }
    int b = c*16 + 15;
    while ((int)gh[b] < k){ k -= (int)gh[b]; --b; }
    thi[grp] = (unsigned)b;
  }
}

// ---------------- K3: compact >bin elements (two-phase: LDS lists + block reservation) ----------------
__global__ __launch_bounds__(256) void k_compact(const float* o0,const float* o1,const float* o2,const float* o3,const float* o4,
                                                 const float* d0,const float* d1,const float* d2,const float* d3,const float* d4,
                                                 const float* anchors, const unsigned* thi,
                                                 unsigned* cnt_gt, unsigned* cnt_eq,
                                                 unsigned long long* cand, unsigned long long* keys){
  int grp = blockIdx.y; int n = grp/5, lvl = grp - n*5;
  int HW = c_HW[lvl], M = 3*HW;
  int base = blockIdx.x * CHUNK;
  if (base >= M) return;
  int end = min(base + CHUNK, M);
  const float* ob = sel5(lvl,o0,o1,o2,o3,o4) + (size_t)n*(size_t)M;
  const float* dl = sel5(lvl,d0,d1,d2,d3,d4);
  unsigned T = thi[grp];
  __shared__ int lgt[1024];              // per-group gt total < 1000 -> block gt <= 999
  __shared__ int leq[TIE_CAP];
  __shared__ unsigned cgt_s, ceq_s, bgt_s, beq_s;
  if (threadIdx.x == 0){ cgt_s = 0u; ceq_s = 0u; }
  __syncthreads();
  for (int i = base + threadIdx.x; i < end; i += 256){
    unsigned s = f2s(ob[i]);
    unsigned sh = s >> 20;
    if (sh > T){
      unsigned k = atomicAdd(&cgt_s, 1u);
      if (k < 1024u) lgt[k] = i;
    } else if (sh == T){
      unsigned k = atomicAdd(&ceq_s, 1u);
      if (k < (unsigned)TIE_CAP) leq[k] = i;
    }
  }
  __syncthreads();
  if (threadIdx.x == 0){
    bgt_s = atomicAdd(&cnt_gt[grp], min(cgt_s, 1024u));
    beq_s = atomicAdd(&cnt_eq[grp], min(ceq_s, (unsigned)TIE_CAP));
  }
  __syncthreads();
  unsigned cg = min(cgt_s, 1024u), ce = min(ceq_s, (unsigned)TIE_CAP);
  unsigned bgt = bgt_s, beq = beq_s;
  unsigned long long* kout = keys + (size_t)n*K_SEL + (size_t)lvl*PRE;
  for (unsigned k = threadIdx.x; k < cg; k += 256){
    int i = lgt[k];
    unsigned s = f2s(ob[i]);
    int a = i / HW; int rem = i - a*HW; int t = rem*3 + a;
    kout[bgt + k] = make_key(s, lvl, t, n, dl, anchors);
  }
  for (unsigned k = threadIdx.x; k < ce; k += 256){
    unsigned e = beq + k;
    if (e < (unsigned)TIE_CAP){
      int i = leq[k];
      unsigned s = f2s(ob[i]);
      int a = i / HW; int rem = i - a*HW; int t = rem*3 + a;
      cand[(size_t)grp*TIE_CAP + e] = ((unsigned long long)(~s) << 19) | (unsigned long long)(unsigned)t;
    }
  }
}

template<int SZ>
__device__ void bitonic(unsigned long long* sk){
  for (int k = 2; k <= SZ; k <<= 1){
    for (int j = k >> 1; j > 0; j >>= 1){
      for (int i = threadIdx.x; i < SZ; i += blockDim.x){
        int ix = i ^ j;
        if (ix > i){
          unsigned long long va = sk[i], vb = sk[ix];
          if ((va > vb) == ((i & k) == 0)){ sk[i] = vb; sk[ix] = va; }
        }
      }
      __syncthreads();
    }
  }
}

// ---------------- K4: boundary selection via rank-select, 4 blocks per group ----------------
// Tie-bin keys unique -> rank = #{smaller} is an exact permutation; candidate with
// rank < need lands at kout[rank] == bitonic result bit-for-bit. Blocks own disjoint
// candidate quarters (writes disjoint) -> 4x parallelism on the HBM-latency gathers
// that dominated rounds 13/14 (warm hbm_bytes 2.6MB at 0.3% occupancy).
__global__ __launch_bounds__(256) void k_tiesel(const float* d0,const float* d1,const float* d2,const float* d3,const float* d4,
                                                const float* anchors,
                                                const unsigned* cnt_gt, const unsigned* cnt_eq,
                                                const unsigned long long* cand, unsigned long long* keys){
  int grp = blockIdx.y; int n = grp/5, lvl = grp - n*5;
  int q = blockIdx.x;                    // candidate quarter [q*1024, q*1024+1024)
  __shared__ unsigned long long sk[TIE_CAP];
  int ne = min((int)cnt_eq[grp], TIE_CAP);
  int c0 = q*1024, c1 = min(ne, c0 + 1024);
  int cg = (int)cnt_gt[grp];
  int need = PRE - cg;
  const float* dl = sel5(lvl,d0,d1,d2,d3,d4);
  unsigned long long* kout = keys + (size_t)n*K_SEL + (size_t)lvl*PRE + cg;
  if (q == 0){  // pathological overflow pad (ne < need): harmless invalid keys
    for (int j = ne + threadIdx.x; j < need; j += 256)
      kout[j] = ((unsigned long long)(~S_NEGINF) << 22);
  }
  if (c0 >= ne) return;
  for (int i = threadIdx.x; i < ne; i += 256)
    sk[i] = cand[(size_t)grp*TIE_CAP + i];
  __syncthreads();
  for (int c = c0 + threadIdx.x; c < c1; c += 256){
    unsigned long long ck = sk[c];
    int rank = 0;
    int i = 0;
    for (; i + 8 <= ne; i += 8){
      rank += (int)(sk[i  ] < ck) + (int)(sk[i+1] < ck)
            + (int)(sk[i+2] < ck) + (int)(sk[i+3] < ck)
            + (int)(sk[i+4] < ck) + (int)(sk[i+5] < ck)
            + (int)(sk[i+6] < ck) + (int)(sk[i+7] < ck);
    }
    for (; i < ne; ++i) rank += (int)(sk[i] < ck);
    if (rank < need){
      unsigned t = (unsigned)(ck & 0x7FFFFu);
      unsigned s = ~((unsigned)(ck >> 19));
      kout[rank] = make_key(s, lvl, (int)t, n, dl, anchors);
    }
  }
}

// ---------------- K5a: sort each (image,level) run (sort only; decode split out) ----------------
__global__ __launch_bounds__(256) void k_sortlvl(unsigned long long* keys){
  int grp = blockIdx.x; int n = grp/5, lvl = grp - n*5;
  __shared__ unsigned long long sk[1024];
  unsigned long long* kp = keys + (size_t)n*K_SEL + (size_t)lvl*PRE;
  for (int i = threadIdx.x; i < 1024; i += 256)
    sk[i] = (i < PRE) ? kp[i] : ~0ULL;
  __syncthreads();
  bitonic<1024>(sk);
  for (int i = threadIdx.x; i < PRE; i += 256) kp[i] = sk[i];
}

// ---------------- K5a2: decode sorted keys -> level-space arrays, 4 blocks/group ----------------
__global__ __launch_bounds__(256) void k_declvl(const unsigned long long* keys,
                                                const float* d0,const float* d1,const float* d2,const float* d3,const float* d4,
                                                const float* anchors,
                                                float4* lbox, float4* lobox, float* loarea, float* lskey){
  int grp = blockIdx.y; int n = grp/5, lvl = grp - n*5;
  int i = blockIdx.x*250 + threadIdx.x;
  if (threadIdx.x >= 250 || i >= PRE) return;
  unsigned long long key = keys[(size_t)n*K_SEL + (size_t)lvl*PRE + i];
  int t = (int)(key & 0x7FFFFu);
  unsigned se = ~((unsigned)(key >> 22));
  const float* dl = sel5(lvl,d0,d1,d2,d3,d4);
  BoxV b = decode_box(lvl, t, n, dl, anchors);
  size_t o = (size_t)grp*PRE + i;
  lbox[o] = make_float4(b.x1,b.y1,b.x2,b.y2);
  lskey[o] = s2f(se);                   // -inf if invalid
  float off = (float)lvl * 1345.0f;     // (IMG+1) batched-NMS offset
  float ox1 = __fadd_rn(b.x1, off), oy1 = __fadd_rn(b.y1, off);
  float ox2 = __fadd_rn(b.x2, off), oy2 = __fadd_rn(b.y2, off);
  lobox[o] = make_float4(ox1,oy1,ox2,oy2);
  loarea[o] = __fmul_rn(__fsub_rn(ox2,ox1), __fsub_rn(oy2,oy1));
}

// ---------------- K5b: global rank of each level element (keys globally unique) ----------------
// rankinfo[rank] = p | (lvl<<10) | (valid<<13)
__global__ __launch_bounds__(256) void k_rank(const unsigned long long* keys, unsigned* rankinfo){
  int grp = blockIdx.x; int n = grp/5, lvl = grp - n*5;
  __shared__ unsigned long long sl[K_SEL];
  for (int i = threadIdx.x; i < K_SEL; i += 256) sl[i] = keys[(size_t)n*K_SEL + i];
  __syncthreads();
  for (int j = threadIdx.x; j < PRE; j += 256){
    unsigned long long k = sl[lvl*PRE + j];
    int rank = j;
    #pragma unroll
    for (int m = 0; m < 5; ++m){
      if (m == lvl) continue;
      const unsigned long long* s = sl + m*PRE;
      int lo = 0, hi = PRE;
      while (lo < hi){ int mid = (lo+hi) >> 1; if (s[mid] < k) lo = mid+1; else hi = mid; }
      rank += lo;
    }
    unsigned se = ~((unsigned)(k >> 22));
    unsigned info = (unsigned)j | ((unsigned)lvl << 10) | ((se != S_NEGINF) ? (1u<<13) : 0u);
    rankinfo[(size_t)n*K_SEL + rank] = info;   // exact permutation of [0,5000)
  }
}

// ---------------- K6a: suppression bit-matrix, ballot + column layout, 4 waves/block ----------------
__global__ __launch_bounds__(256) void k_ioumat_lvl(const float4* lobox, const float* loarea, unsigned* lmat){
  int grp = blockIdx.y;                  // n*5 + L
  int wblk = blockIdx.x;                 // j-block: j = wblk*64 + lane
  int tid = threadIdx.x;
  int lane = tid & 63, q = tid >> 6;
  __shared__ float sx1[PRE], sy1[PRE], sx2[PRE], sy2[PRE], sar[PRE];
  for (int i = tid; i < PRE; i += 256){
    float4 bb = lobox[(size_t)grp*PRE + i];
    sx1[i]=bb.x; sy1[i]=bb.y; sx2[i]=bb.z; sy2[i]=bb.w;
    sar[i]=loarea[(size_t)grp*PRE + i];
  }
  __syncthreads();
  int j = wblk*64 + lane;
  float jx1=0.f,jy1=0.f,jx2=0.f,jy2=0.f,ja=0.f;
  if (j < PRE){
    float4 bb = lobox[(size_t)grp*PRE + j];
    jx1=bb.x; jy1=bb.y; jx2=bb.z; jy2=bb.w; ja=loarea[(size_t)grp*PRE + j];
  }
  unsigned* mg = lmat + (size_t)grp*GRPW + (size_t)wblk*2*PRE;
  int pmax = min(PRE, wblk*64 + 63);     // rows p >= pmax: no j>p in this block
  int q0 = q*250, q1 = q0 + 250;
  int pm = min(q1, pmax);

#define IOU_HIT(P, OUT) { \
    float bx1=sx1[P], by1=sy1[P], bx2=sx2[P], by2=sy2[P], ba=sar[P]; \
    float ltx = fmaxf(bx1, jx1), lty = fmaxf(by1, jy1); \
    float rbx = fminf(bx2, jx2), rby = fminf(by2, jy2); \
    float ww = fmaxf(__fsub_rn(rbx,ltx), 0.0f); \
    float hh = fmaxf(__fsub_rn(rby,lty), 0.0f); \
    float inter = __fmul_rn(ww,hh); \
    float uni = __fsub_rn(__fadd_rn(ba, ja), inter); \
    OUT = (__fdiv_rn(inter,uni) > 0.7f) && (j > (P)) && (j < PRE); }

  int p = q0;
  for (; p + 4 <= pm; p += 4){
    bool h0,h1,h2,h3;
    IOU_HIT(p,   h0);
    IOU_HIT(p+1, h1);
    IOU_HIT(p+2, h2);
    IOU_HIT(p+3, h3);
    unsigned long long b0 = __ballot(h0), b1 = __ballot(h1);
    unsigned long long b2 = __ballot(h2), b3 = __ballot(h3);
    if ((lane & 31) == 0){
      int d = lane >> 5;
      mg[(p  )*2 + d] = (lane==0) ? (unsigned)b0 : (unsigned)(b0>>32);
      mg[(p+1)*2 + d] = (lane==0) ? (unsigned)b1 : (unsigned)(b1>>32);
      mg[(p+2)*2 + d] = (lane==0) ? (unsigned)b2 : (unsigned)(b2>>32);
      mg[(p+3)*2 + d] = (lane==0) ? (unsigned)b3 : (unsigned)(b3>>32);
    }
  }
  for (; p < pm; ++p){
    bool h; IOU_HIT(p, h);
    unsigned long long bal = __ballot(h);
    if ((lane & 31) == 0)
      mg[p*2 + (lane>>5)] = (lane==0) ? (unsigned)bal : (unsigned)(bal>>32);
  }
#undef IOU_HIT
  int zs = (pm > q0 ? pm : q0);
  for (int w = zs*2 + lane; w < q1*2; w += 64) mg[w] = 0u;   // contiguous zero-fill
}

// ---------------- K6b: tile-parallel greedy scan, latency-batched TPROC ----------------
__global__ __launch_bounds__(64) void k_scan_nms5(const unsigned* rankinfo, const unsigned* lmat,
                                                  const float4* lbox, const float* lskey, float* out){
  __shared__ unsigned lrows[64][36];     // row-major tile; stride 36 words
  __shared__ unsigned lsup[160];         // 5 levels x 32 words suppression state
  int n = blockIdx.x; int lane = threadIdx.x;
  int n5 = n*5;
  const unsigned* rin = rankinfo + (size_t)n*K_SEL;
  float* outn = out + (size_t)n*PRE*5;
  for (int i = lane; i < PRE*5; i += 64) outn[i] = 0.0f;   // own-image zero (replaces memset)
  for (int i = lane; i < 160; i += 64) lsup[i] = 0u;
  int kept_total = 0;
  uint2 Pa,Pb,Pc,Pd,Pe,Pf,Pg,Ph,Pi,Pj,Pk,Pl,Pm,Pn,Po,Pp;  // 16x8B staging
  float4 boxP; float scP = 0.f;
  unsigned infoC, infoN;
  int rgrp = lane >> 4;                  // 0..3: row subgroup
  unsigned wboff = (unsigned)(lane & 15) * (2u*PRE);  // my wblk's column segment
  int wb2 = (lane & 15) << 1;            // word index within row

#define SLOAD(INFO) { \
    unsigned L_ = ((INFO)>>10)&7u; unsigned p_ = (INFO) & 1023u; \
    unsigned rowu_ = ((unsigned)n5 + L_)*GRPW + p_*2u; \
    unsigned rb_; \
    rb_ = __shfl(rowu_,  0 + rgrp); Pa = *(const uint2*)(lmat + rb_ + wboff); \
    rb_ = __shfl(rowu_,  4 + rgrp); Pb = *(const uint2*)(lmat + rb_ + wboff); \
    rb_ = __shfl(rowu_,  8 + rgrp); Pc = *(const uint2*)(lmat + rb_ + wboff); \
    rb_ = __shfl(rowu_, 12 + rgrp); Pd = *(const uint2*)(lmat + rb_ + wboff); \
    rb_ = __shfl(rowu_, 16 + rgrp); Pe = *(const uint2*)(lmat + rb_ + wboff); \
    rb_ = __shfl(rowu_, 20 + rgrp); Pf = *(const uint2*)(lmat + rb_ + wboff); \
    rb_ = __shfl(rowu_, 24 + rgrp); Pg = *(const uint2*)(lmat + rb_ + wboff); \
    rb_ = __shfl(rowu_, 28 + rgrp); Ph = *(const uint2*)(lmat + rb_ + wboff); \
    rb_ = __shfl(rowu_, 32 + rgrp); Pi = *(const uint2*)(lmat + rb_ + wboff); \
    rb_ = __shfl(rowu_, 36 + rgrp); Pj = *(const uint2*)(lmat + rb_ + wboff); \
    rb_ = __shfl(rowu_, 40 + rgrp); Pk = *(const uint2*)(lmat + rb_ + wboff); \
    rb_ = __shfl(rowu_, 44 + rgrp); Pl = *(const uint2*)(lmat + rb_ + wboff); \
    rb_ = __shfl(rowu_, 48 + rgrp); Pm = *(const uint2*)(lmat + rb_ + wboff); \
    rb_ = __shfl(rowu_, 52 + rgrp); Pn = *(const uint2*)(lmat + rb_ + wboff); \
    rb_ = __shfl(rowu_, 56 + rgrp); Po = *(const uint2*)(lmat + rb_ + wboff); \
    rb_ = __shfl(rowu_, 60 + rgrp); Pp = *(const uint2*)(lmat + rb_ + wboff); \
    size_t bi_ = (size_t)((unsigned)n5 + L_)*PRE + p_; \
    boxP = lbox[bi_]; scP = lskey[bi_]; }

#define SWRITE() { \
    *(uint2*)&lrows[ 0 + rgrp][wb2] = Pa; *(uint2*)&lrows[ 4 + rgrp][wb2] = Pb; \
    *(uint2*)&lrows[ 8 + rgrp][wb2] = Pc; *(uint2*)&lrows[12 + rgrp][wb2] = Pd; \
    *(uint2*)&lrows[16 + rgrp][wb2] = Pe; *(uint2*)&lrows[20 + rgrp][wb2] = Pf; \
    *(uint2*)&lrows[24 + rgrp][wb2] = Pg; *(uint2*)&lrows[28 + rgrp][wb2] = Ph; \
    *(uint2*)&lrows[32 + rgrp][wb2] = Pi; *(uint2*)&lrows[36 + rgrp][wb2] = Pj; \
    *(uint2*)&lrows[40 + rgrp][wb2] = Pk; *(uint2*)&lrows[44 + rgrp][wb2] = Pl; \
    *(uint2*)&lrows[48 + rgrp][wb2] = Pm; *(uint2*)&lrows[52 + rgrp][wb2] = Pn; \
    *(uint2*)&lrows[56 + rgrp][wb2] = Po; *(uint2*)&lrows[60 + rgrp][wb2] = Pp; }

#define GRP16(B, ACC, SH) { \
    unsigned q0_=lrows[(B)+ 0][idxw_], q1_=lrows[(B)+ 1][idxw_], \
             q2_=lrows[(B)+ 2][idxw_], q3_=lrows[(B)+ 3][idxw_], \
             q4_=lrows[(B)+ 4][idxw_], q5_=lrows[(B)+ 5][idxw_], \
             q6_=lrows[(B)+ 6][idxw_], q7_=lrows[(B)+ 7][idxw_], \
             q8_=lrows[(B)+ 8][idxw_], q9_=lrows[(B)+ 9][idxw_], \
             qa_=lrows[(B)+10][idxw_], qb_=lrows[(B)+11][idxw_], \
             qc_=lrows[(B)+12][idxw_], qd_=lrows[(B)+13][idxw_], \
             qe_=lrows[(B)+14][idxw_], qf_=lrows[(B)+15][idxw_]; \
    ACC |= (((q0_>>pb_)&1u)<<((SH)+ 0)) | (((q1_>>pb_)&1u)<<((SH)+ 1)) \
         | (((q2_>>pb_)&1u)<<((SH)+ 2)) | (((q3_>>pb_)&1u)<<((SH)+ 3)) \
         | (((q4_>>pb_)&1u)<<((SH)+ 4)) | (((q5_>>pb_)&1u)<<((SH)+ 5)) \
         | (((q6_>>pb_)&1u)<<((SH)+ 6)) | (((q7_>>pb_)&1u)<<((SH)+ 7)) \
         | (((q8_>>pb_)&1u)<<((SH)+ 8)) | (((q9_>>pb_)&1u)<<((SH)+ 9)) \
         | (((qa_>>pb_)&1u)<<((SH)+10)) | (((qb_>>pb_)&1u)<<((SH)+11)) \
         | (((qc_>>pb_)&1u)<<((SH)+12)) | (((qd_>>pb_)&1u)<<((SH)+13)) \
         | (((qe_>>pb_)&1u)<<((SH)+14)) | (((qf_>>pb_)&1u)<<((SH)+15)); }

#define TPROC(INFO, BOX, SC, baseexpr) { \
    int base_ = (baseexpr); \
    unsigned L_ = ((INFO)>>10)&7u; unsigned p_ = (INFO) & 1023u; \
    int idxw_ = (int)(p_ >> 5); unsigned pb_ = p_ & 31u; \
    unsigned long long lb0_=__ballot(L_==0u), lb1_=__ballot(L_==1u), \
                       lb2_=__ballot(L_==2u), lb3_=__ballot(L_==3u), lb4_=__ballot(L_==4u); \
    unsigned long long myLvl_ = (L_==0u)?lb0_:(L_==1u)?lb1_:(L_==2u)?lb2_:(L_==3u)?lb3_:lb4_; \
    unsigned sw_ = lsup[L_*32u + (unsigned)idxw_]; \
    bool ok_ = ((((INFO)>>13)&1u)!=0u) && (base_ + lane < K_SEL) && (((sw_>>pb_)&1u)==0u); \
    unsigned long long cand_ = __ballot(ok_); \
    unsigned alo_ = 0u, ahi_ = 0u; \
    GRP16( 0, alo_,  0); GRP16(16, alo_, 16); \
    GRP16(32, ahi_,  0); GRP16(48, ahi_, 16); \
    unsigned long long cm_ = ((((unsigned long long)ahi_)<<32)|(unsigned long long)alo_) & myLvl_; \
    unsigned long long keptM_ = 0ull; \
    while (cand_){ \
      bool safe_ = (((cand_>>lane)&1ull)!=0ull) && ((cm_ & cand_)==0ull); \
      unsigned long long nk_ = __ballot(safe_); \
      keptM_ |= nk_; \
      bool dead_ = (((cand_>>lane)&1ull)!=0ull) && ((cm_ & nk_)!=0ull); \
      cand_ &= ~(nk_ | __ballot(dead_)); \
    } \
    if (((keptM_>>lane)&1ull)!=0ull){ \
      unsigned sb_ = L_*32u; \
      _Pragma("unroll") \
      for (int k_ = 0; k_ < 32; ++k_){ \
        unsigned w_ = (unsigned)((k_+lane)&31); \
        atomicOr(&lsup[sb_+w_], lrows[lane][w_]); \
      } \
    } \
    int pos_ = kept_total + (int)__popcll(keptM_ & ((1ull<<lane)-1ull)); \
    if ((((keptM_>>lane)&1ull)!=0ull) && pos_ < PRE){ \
      float* orow_ = outn + (size_t)pos_*5; \
      orow_[0]=(BOX).x; orow_[1]=(BOX).y; orow_[2]=(BOX).z; orow_[3]=(BOX).w; orow_[4]=(SC); \
    } \
    kept_total += (int)__popcll(keptM_); \
    asm volatile("s_waitcnt lgkmcnt(0)" ::: "memory"); \
  }

  infoC = rin[lane];
  SLOAD(infoC);                          // tile 0 rows -> regs, box -> boxP
  SWRITE();                              // tile 0 rows -> LDS
  float4 boxC = boxP; float scC = scP;
  infoN = rin[64 + lane];

  for (int t = 0; t < TILES; ++t){
    if (t+1 < TILES) SLOAD(infoN);       // issue next tile's loads (rows + box)
    asm volatile("s_waitcnt lgkmcnt(0)" ::: "memory");   // lrows writes visible
    TPROC(infoC, boxC, scC, t*64);
    if (kept_total >= PRE) break;
    if (t+1 < TILES){
      SWRITE();                          // waits next tile's loads (covered by TPROC)
      boxC = boxP; scC = scP;
      infoC = infoN;
      if (t+2 < TILES){
        int nx = (t+2)*64 + lane; if (nx > K_SEL-1) nx = K_SEL-1;
        infoN = rin[nx];
      }
    }
  }
#undef SLOAD
#undef SWRITE
#undef GRP16
#undef TPROC
}

// ---------------- fallback path (ws too small): round-3 kernels ----------------
__global__ __launch_bounds__(256) void k_sortimg(const unsigned long long* keys,
                                                 const float* d0,const float* d1,const float* d2,const float* d3,const float* d4,
                                                 const float* anchors,
                                                 float4* sbox, float* sskey, int* slvl){
  int n = blockIdx.x;
  __shared__ unsigned long long sk[8192];
  for (int i = threadIdx.x; i < 8192; i += 256)
    sk[i] = (i < K_SEL) ? keys[(size_t)n*K_SEL + i] : ~0ULL;
  __syncthreads();
  bitonic<8192>(sk);
  for (int r = threadIdx.x; r < K_SEL; r += 256){
    unsigned long long key = sk[r];
    int t = (int)(key & 0x7FFFFu);
    int lvl = (int)((key >> 19) & 7u);
    unsigned se = ~((unsigned)(key >> 22));
    const float* dl = sel5(lvl,d0,d1,d2,d3,d4);
    BoxV b = decode_box(lvl, t, n, dl, anchors);
    sbox[(size_t)n*K_SEL + r] = make_float4(b.x1,b.y1,b.x2,b.y2);
    sskey[(size_t)n*K_SEL + r] = s2f(se);
    slvl[(size_t)n*K_SEL + r] = lvl;
  }
}

__global__ __launch_bounds__(256) void k_nms(const float4* sbox, const float* sskey, const int* slvl, float* out){
  int n = blockIdx.x, tid = threadIdx.x;
  __shared__ float kx1[PRE], ky1[PRE], kx2[PRE], ky2[PRE], kar[PRE];
  __shared__ int klv[PRE];
  __shared__ int nv_s, flag_s;
  for (int i = tid; i < PRE*5; i += 256) out[(size_t)n*PRE*5 + i] = 0.0f;
  if (tid == 0){ nv_s = 0; flag_s = 0; }
  __syncthreads();
  int c = 0;
  for (int i = tid; i < K_SEL; i += 256)
    if (sskey[(size_t)n*K_SEL + i] != -INFINITY) ++c;
  atomicAdd(&nv_s, c);
  __syncthreads();
  int nvalid = nv_s;
  int kept = 0;
  for (int i = 0; i < nvalid; ++i){
    float4 b = sbox[(size_t)n*K_SEL + i];
    int lv = slvl[(size_t)n*K_SEL + i];
    float off = (float)lv * 1345.0f;
    float ox1 = __fadd_rn(b.x, off), oy1 = __fadd_rn(b.y, off);
    float ox2 = __fadd_rn(b.z, off), oy2 = __fadd_rn(b.w, off);
    float area = __fmul_rn(__fsub_rn(ox2,ox1), __fsub_rn(oy2,oy1));
    bool hit = false;
    for (int j = tid; j < kept; j += 256){
      if (klv[j] == lv){
        float ltx = fmaxf(kx1[j], ox1), lty = fmaxf(ky1[j], oy1);
        float rbx = fminf(kx2[j], ox2), rby = fminf(ky2[j], oy2);
        float w = fmaxf(__fsub_rn(rbx,ltx), 0.0f);
        float h = fmaxf(__fsub_rn(rby,lty), 0.0f);
        float inter = __fmul_rn(w,h);
        float uni = __fsub_rn(__fadd_rn(kar[j], area), inter);
        if (__fdiv_rn(inter,uni) > 0.7f) hit = true;
      }
    }
    if (hit) flag_s = 1;
    __syncthreads();
    int sup = flag_s;
    __syncthreads();
    if (!sup){
      if (tid == 0){
        kx1[kept]=ox1; ky1[kept]=oy1; kx2[kept]=ox2; ky2[kept]=oy2; kar[kept]=area; klv[kept]=lv;
        float* orow = out + (size_t)n*PRE*5 + (size_t)kept*5;
        orow[0]=b.x; orow[1]=b.y; orow[2]=b.z; orow[3]=b.w;
        orow[4]=sskey[(size_t)n*K_SEL + i];
      }
      ++kept;
    }
    if (tid == 0) flag_s = 0;
    __syncthreads();
    if (kept == PRE) break;
  }
}

extern "C" void kernel_launch(void* const* d_in, const int* in_sizes, int n_in,
                              void* d_out, int out_size, void* d_ws, size_t ws_size,
                              hipStream_t stream) {
  bool interleaved = (in_sizes[1] == 4*in_sizes[0]);
  const float* obj[5]; const float* dlt[5];
  for (int i = 0; i < 5; ++i){
    if (interleaved){ obj[i] = (const float*)d_in[2*i]; dlt[i] = (const float*)d_in[2*i+1]; }
    else            { obj[i] = (const float*)d_in[i];   dlt[i] = (const float*)d_in[5+i]; }
  }
  const float* anchors = (const float*)d_in[10];

  char* ws = (char*)d_ws;
  unsigned* hist            = (unsigned*)(ws);                     // 655360
  unsigned* cnt_gt          = (unsigned*)(ws + 655360);            // 160
  unsigned* cnt_eq          = (unsigned*)(ws + 655520);            // 160
  unsigned* thi             = (unsigned*)(ws + 655680);            // 160 -> counters end 655840
  unsigned long long* cand  = (unsigned long long*)(ws + 655840);  // 1310720 -> 1966560
  unsigned long long* keys  = (unsigned long long*)(ws + 1966560); // 320000 -> 2286560
  float4* lbox              = (float4*)(ws + 2286560);             // 640000 -> 2926560
  float4* lobox             = (float4*)(ws + 2926560);             // 640000 -> 3566560
  float* loarea             = (float*)(ws + 3566560);              // 160000 -> 3726560
  float* lskey              = (float*)(ws + 3726560);              // 160000 -> 3886560
  unsigned* rankinfo        = (unsigned*)(ws + 3886560);           // 160000 -> 4046560
  unsigned* lmat            = (unsigned*)(ws + 4046560);           // 5120000 -> 9166560
  float4* sbox              = (float4*)(ws + 9166560);             // fallback: 640000 -> 9806560
  float* sskey              = (float*)(ws + 9806560);              // 160000 -> 9966560
  int* slvl                 = (int*)(ws + 9966560);                // 160000 -> 10126560
  const size_t NEED = 10126560;

  hipMemsetAsync(ws, 0, 655840, stream);   // hist + counters

  dim3 gChunk(42, 40);                   // 42 chunks x 8192 covers level-0's 338688
  k_hist<<<gChunk, 256, 0, stream>>>(obj[0],obj[1],obj[2],obj[3],obj[4], hist);
  k_scan<<<40, 256, 0, stream>>>(hist, thi);
  k_compact<<<gChunk, 256, 0, stream>>>(obj[0],obj[1],obj[2],obj[3],obj[4],
                                        dlt[0],dlt[1],dlt[2],dlt[3],dlt[4],
                                        anchors, thi, cnt_gt, cnt_eq, cand, keys);
  k_tiesel<<<dim3(4, 40), 256, 0, stream>>>(dlt[0],dlt[1],dlt[2],dlt[3],dlt[4], anchors,
                                            cnt_gt, cnt_eq, cand, keys);
  if (ws_size >= NEED){
    k_sortlvl<<<40, 256, 0, stream>>>(keys);
    k_declvl<<<dim3(4, 40), 256, 0, stream>>>(keys, dlt[0],dlt[1],dlt[2],dlt[3],dlt[4], anchors,
                                              lbox, lobox, loarea, lskey);
    k_rank<<<40, 256, 0, stream>>>(keys, rankinfo);
    k_ioumat_lvl<<<dim3(16, 40), 256, 0, stream>>>(lobox, loarea, lmat);
    k_scan_nms5<<<8, 64, 0, stream>>>(rankinfo, lmat, lbox, lskey, (float*)d_out);
  } else {
    k_sortimg<<<8, 256, 0, stream>>>(keys, dlt[0],dlt[1],dlt[2],dlt[3],dlt[4], anchors,
                                     sbox, sskey, slvl);
    k_nms<<<8, 256, 0, stream>>>(sbox, sskey, slvl, (float*)d_out);
  }
}

// Round 16
// 221.117 us; speedup vs baseline: 1.2992x; 1.2177x over previous
//
#include <hip/hip_runtime.h>
#include <cmath>

#define N_IMG   8
#define PRE     1000
#define K_SEL   5000
#define NBIN    4096
#define TIE_CAP 4096
#define IMG_F   1344.0f
#define S_NEGINF 0x007FFFFFu
#define TILES   79             // ceil(5000/64)
#define GRPW    32000          // words per grp in lmat: 16 wblk x 1000 p x 2
#define CHUNK   8192           // elements per block in k_hist/k_compact

__constant__ int c_W[5]   = {336,168,84,42,21};
__constant__ int c_HW[5]  = {112896,28224,7056,1764,441};
__constant__ int c_OFF[5] = {0,338688,423360,444528,449820};

__device__ __forceinline__ unsigned f2s(float f){
  unsigned u = __float_as_uint(f);
  return (u & 0x80000000u) ? ~u : (u | 0x80000000u);
}
__device__ __forceinline__ float s2f(unsigned s){
  unsigned u = (s & 0x80000000u) ? (s & 0x7FFFFFFFu) : ~s;
  return __uint_as_float(u);
}
__device__ __forceinline__ const float* sel5(int l, const float* p0,const float* p1,const float* p2,const float* p3,const float* p4){
  switch(l){case 0:return p0;case 1:return p1;case 2:return p2;case 3:return p3;default:return p4;}
}

struct BoxV { float x1,y1,x2,y2; bool valid; };

// Bit-faithful torchvision BoxCoder.decode + clip + min-size validity.
__device__ BoxV decode_box(int lvl, int t, int n, const float* dl, const float* anchors){
  int HW = c_HW[lvl], W = c_W[lvl];
  int a = t % 3, pos = t / 3;          // t = (h*W+w)*3 + a
  int h = pos / W, w = pos - h*W;
  int g = c_OFF[lvl] + t;
  const float* an = anchors + (size_t)4*(size_t)g;
  float a0=an[0], a1=an[1], a2=an[2], a3=an[3];
  float aw = __fsub_rn(a2,a0), ah = __fsub_rn(a3,a1);
  float acx = __fadd_rn(a0, __fmul_rn(0.5f,aw));
  float acy = __fadd_rn(a1, __fmul_rn(0.5f,ah));
  const float* dp = dl + ((size_t)n*12 + (size_t)a*4)*(size_t)HW + (size_t)h*W + (size_t)w;
  float dx = dp[0], dy = dp[HW], dwv = dp[2*(size_t)HW], dhv = dp[3*(size_t)HW];
  const float CLAMP = (float)4.135166556742356;  // log(1000/16)
  dwv = fminf(dwv, CLAMP); dhv = fminf(dhv, CLAMP);
  float pcx = __fadd_rn(__fmul_rn(dx,aw), acx);
  float pcy = __fadd_rn(__fmul_rn(dy,ah), acy);
  float pw = __fmul_rn((float)::exp((double)dwv), aw);
  float ph = __fmul_rn((float)::exp((double)dhv), ah);
  float hx = __fmul_rn(0.5f,pw), hy = __fmul_rn(0.5f,ph);
  BoxV b;
  b.x1 = fminf(fmaxf(__fsub_rn(pcx,hx),0.0f),IMG_F);
  b.y1 = fminf(fmaxf(__fsub_rn(pcy,hy),0.0f),IMG_F);
  b.x2 = fminf(fmaxf(__fadd_rn(pcx,hx),0.0f),IMG_F);
  b.y2 = fminf(fmaxf(__fadd_rn(pcy,hy),0.0f),IMG_F);
  b.valid = (__fsub_rn(b.x2,b.x1) >= 1e-3f) && (__fsub_rn(b.y2,b.y1) >= 1e-3f);
  return b;
}

// key = (~s_eff)<<22 | lvl<<19 | t : ascending sort == (score desc, level asc, idx asc)
__device__ unsigned long long make_key(unsigned s, int lvl, int t, int n, const float* dl, const float* anchors){
  BoxV b = decode_box(lvl,t,n,dl,anchors);
  unsigned se = b.valid ? s : S_NEGINF;     // invalid -> skey = -inf
  return ((unsigned long long)(~se) << 22) | ((unsigned long long)(unsigned)lvl << 19) | (unsigned long long)(unsigned)t;
}

// ---------------- K1: per-(image,level) 12-bit score histogram (chunked grid) ----------------
__global__ __launch_bounds__(256) void k_hist(const float* o0,const float* o1,const float* o2,const float* o3,const float* o4,
                                              unsigned* hist){
  int grp = blockIdx.y; int n = grp/5, lvl = grp - n*5;
  int HW = c_HW[lvl], M = 3*HW;
  int base = blockIdx.x * CHUNK;
  if (base >= M) return;                 // idle block for short levels
  int end = min(base + CHUNK, M);
  const float* ob = sel5(lvl,o0,o1,o2,o3,o4) + (size_t)n*(size_t)M;
  __shared__ unsigned lh[NBIN];
  for (int b = threadIdx.x; b < NBIN; b += 256) lh[b] = 0;
  __syncthreads();
  for (int i = base + threadIdx.x; i < end; i += 256){
    unsigned s = f2s(ob[i]);
    atomicAdd(&lh[s >> 20], 1u);
  }
  __syncthreads();
  unsigned* gh = hist + (size_t)grp*NBIN;
  for (int b = threadIdx.x; b < NBIN; b += 256){ unsigned v = lh[b]; if (v) atomicAdd(&gh[b], v); }
}

// ---------------- K2: find bin containing the 1000th-largest score ----------------
__global__ __launch_bounds__(256) void k_scan(const unsigned* hist, unsigned* thi){
  int grp = blockIdx.x;
  const unsigned* gh = hist + (size_t)grp*NBIN;
  __shared__ unsigned part[256];
  unsigned ssum = 0;
  int base = threadIdx.x*16;
  for (int b = base; b < base+16; ++b) ssum += gh[b];
  part[threadIdx.x] = ssum;
  __syncthreads();
  if (threadIdx.x == 0){
    int k = PRE;
    int c = 255;
    while ((int)part[c] < k){ k -= (int)part[c]; --c; }
    int b = c*16 + 15;
    while ((int)gh[b] < k){ k -= (int)gh[b]; --b; }
    thi[grp] = (unsigned)b;
  }
}

// ---------------- K3: compact >bin elements (two-phase: LDS lists + block reservation) ----------------
__global__ __launch_bounds__(256) void k_compact(const float* o0,const float* o1,const float* o2,const float* o3,const float* o4,
                                                 const float* d0,const float* d1,const float* d2,const float* d3,const float* d4,
                                                 const float* anchors, const unsigned* thi,
                                                 unsigned* cnt_gt, unsigned* cnt_eq,
                                                 unsigned long long* cand, unsigned long long* keys){
  int grp = blockIdx.y; int n = grp/5, lvl = grp - n*5;
  int HW = c_HW[lvl], M = 3*HW;
  int base = blockIdx.x * CHUNK;
  if (base >= M) return;
  int end = min(base + CHUNK, M);
  const float* ob = sel5(lvl,o0,o1,o2,o3,o4) + (size_t)n*(size_t)M;
  const float* dl = sel5(lvl,d0,d1,d2,d3,d4);
  unsigned T = thi[grp];
  __shared__ int lgt[1024];              // per-group gt total < 1000 -> block gt <= 999
  __shared__ int leq[TIE_CAP];
  __shared__ unsigned cgt_s, ceq_s, bgt_s, beq_s;
  if (threadIdx.x == 0){ cgt_s = 0u; ceq_s = 0u; }
  __syncthreads();
  for (int i = base + threadIdx.x; i < end; i += 256){
    unsigned s = f2s(ob[i]);
    unsigned sh = s >> 20;
    if (sh > T){
      unsigned k = atomicAdd(&cgt_s, 1u);
      if (k < 1024u) lgt[k] = i;
    } else if (sh == T){
      unsigned k = atomicAdd(&ceq_s, 1u);
      if (k < (unsigned)TIE_CAP) leq[k] = i;
    }
  }
  __syncthreads();
  if (threadIdx.x == 0){
    bgt_s = atomicAdd(&cnt_gt[grp], min(cgt_s, 1024u));
    beq_s = atomicAdd(&cnt_eq[grp], min(ceq_s, (unsigned)TIE_CAP));
  }
  __syncthreads();
  unsigned cg = min(cgt_s, 1024u), ce = min(ceq_s, (unsigned)TIE_CAP);
  unsigned bgt = bgt_s, beq = beq_s;
  unsigned long long* kout = keys + (size_t)n*K_SEL + (size_t)lvl*PRE;
  for (unsigned k = threadIdx.x; k < cg; k += 256){
    int i = lgt[k];
    unsigned s = f2s(ob[i]);
    int a = i / HW; int rem = i - a*HW; int t = rem*3 + a;
    kout[bgt + k] = make_key(s, lvl, t, n, dl, anchors);
  }
  for (unsigned k = threadIdx.x; k < ce; k += 256){
    unsigned e = beq + k;
    if (e < (unsigned)TIE_CAP){
      int i = leq[k];
      unsigned s = f2s(ob[i]);
      int a = i / HW; int rem = i - a*HW; int t = rem*3 + a;
      cand[(size_t)grp*TIE_CAP + e] = ((unsigned long long)(~s) << 19) | (unsigned long long)(unsigned)t;
    }
  }
}

template<int SZ>
__device__ void bitonic(unsigned long long* sk){
  for (int k = 2; k <= SZ; k <<= 1){
    for (int j = k >> 1; j > 0; j >>= 1){
      for (int i = threadIdx.x; i < SZ; i += blockDim.x){
        int ix = i ^ j;
        if (ix > i){
          unsigned long long va = sk[i], vb = sk[ix];
          if ((va > vb) == ((i & k) == 0)){ sk[i] = vb; sk[ix] = va; }
        }
      }
      __syncthreads();
    }
  }
}

// ---------------- K4: boundary selection via rank-select, 16 runtime chunks/group ----------------
// Round-15 lesson: ne ~ 50-400 < fixed 1024 quarters -> only q0 worked (40 blocks).
// Runtime chunk = ceil(ne/16) gives all 640 blocks work -> 16x outstanding scattered
// decode gathers (measured: 2.65MB at 38GB/s effective == the whole 70us).
__global__ __launch_bounds__(256) void k_tiesel(const float* d0,const float* d1,const float* d2,const float* d3,const float* d4,
                                                const float* anchors,
                                                const unsigned* cnt_gt, const unsigned* cnt_eq,
                                                const unsigned long long* cand, unsigned long long* keys){
  int grp = blockIdx.y; int n = grp/5, lvl = grp - n*5;
  int q = blockIdx.x;                    // 16 runtime chunks
  __shared__ unsigned long long sk[TIE_CAP];
  int ne = min((int)cnt_eq[grp], TIE_CAP);
  int cg = (int)cnt_gt[grp];
  int need = PRE - cg;
  const float* dl = sel5(lvl,d0,d1,d2,d3,d4);
  unsigned long long* kout = keys + (size_t)n*K_SEL + (size_t)lvl*PRE + cg;
  if (q == 0){  // pathological overflow pad (ne < need): harmless invalid keys
    for (int j = ne + threadIdx.x; j < need; j += 256)
      kout[j] = ((unsigned long long)(~S_NEGINF) << 22);
  }
  int chunk = (ne + 15) >> 4;
  int c0 = q*chunk, c1 = min(ne, c0 + chunk);
  if (c0 >= ne) return;
  for (int i = threadIdx.x; i < ne; i += 256)
    sk[i] = cand[(size_t)grp*TIE_CAP + i];
  __syncthreads();
  for (int c = c0 + threadIdx.x; c < c1; c += 256){
    unsigned long long ck = sk[c];
    int rank = 0;
    int i = 0;
    for (; i + 8 <= ne; i += 8){
      rank += (int)(sk[i  ] < ck) + (int)(sk[i+1] < ck)
            + (int)(sk[i+2] < ck) + (int)(sk[i+3] < ck)
            + (int)(sk[i+4] < ck) + (int)(sk[i+5] < ck)
            + (int)(sk[i+6] < ck) + (int)(sk[i+7] < ck);
    }
    for (; i < ne; ++i) rank += (int)(sk[i] < ck);
    if (rank < need){
      unsigned t = (unsigned)(ck & 0x7FFFFu);
      unsigned s = ~((unsigned)(ck >> 19));
      kout[rank] = make_key(s, lvl, (int)t, n, dl, anchors);
    }
  }
}

// ---------------- K5a: sort each (image,level) run (sort only; decode split out) ----------------
__global__ __launch_bounds__(256) void k_sortlvl(unsigned long long* keys){
  int grp = blockIdx.x; int n = grp/5, lvl = grp - n*5;
  __shared__ unsigned long long sk[1024];
  unsigned long long* kp = keys + (size_t)n*K_SEL + (size_t)lvl*PRE;
  for (int i = threadIdx.x; i < 1024; i += 256)
    sk[i] = (i < PRE) ? kp[i] : ~0ULL;
  __syncthreads();
  bitonic<1024>(sk);
  for (int i = threadIdx.x; i < PRE; i += 256) kp[i] = sk[i];
}

// ---------------- K5a2: decode sorted keys -> level-space arrays, 8 blocks/group ----------------
__global__ __launch_bounds__(256) void k_declvl(const unsigned long long* keys,
                                                const float* d0,const float* d1,const float* d2,const float* d3,const float* d4,
                                                const float* anchors,
                                                float4* lbox, float4* lobox, float* loarea, float* lskey){
  int grp = blockIdx.y; int n = grp/5, lvl = grp - n*5;
  if (threadIdx.x >= 125) return;
  int i = blockIdx.x*125 + threadIdx.x;  // 8 x 125 = 1000
  unsigned long long key = keys[(size_t)n*K_SEL + (size_t)lvl*PRE + i];
  int t = (int)(key & 0x7FFFFu);
  unsigned se = ~((unsigned)(key >> 22));
  const float* dl = sel5(lvl,d0,d1,d2,d3,d4);
  BoxV b = decode_box(lvl, t, n, dl, anchors);
  size_t o = (size_t)grp*PRE + i;
  lbox[o] = make_float4(b.x1,b.y1,b.x2,b.y2);
  lskey[o] = s2f(se);                   // -inf if invalid
  float off = (float)lvl * 1345.0f;     // (IMG+1) batched-NMS offset
  float ox1 = __fadd_rn(b.x1, off), oy1 = __fadd_rn(b.y1, off);
  float ox2 = __fadd_rn(b.x2, off), oy2 = __fadd_rn(b.y2, off);
  lobox[o] = make_float4(ox1,oy1,ox2,oy2);
  loarea[o] = __fmul_rn(__fsub_rn(ox2,ox1), __fsub_rn(oy2,oy1));
}

// ---------------- K5b: global rank of each level element (keys globally unique) ----------------
// rankinfo[rank] = p | (lvl<<10) | (valid<<13)
__global__ __launch_bounds__(256) void k_rank(const unsigned long long* keys, unsigned* rankinfo){
  int grp = blockIdx.x; int n = grp/5, lvl = grp - n*5;
  __shared__ unsigned long long sl[K_SEL];
  for (int i = threadIdx.x; i < K_SEL; i += 256) sl[i] = keys[(size_t)n*K_SEL + i];
  __syncthreads();
  for (int j = threadIdx.x; j < PRE; j += 256){
    unsigned long long k = sl[lvl*PRE + j];
    int rank = j;
    #pragma unroll
    for (int m = 0; m < 5; ++m){
      if (m == lvl) continue;
      const unsigned long long* s = sl + m*PRE;
      int lo = 0, hi = PRE;
      while (lo < hi){ int mid = (lo+hi) >> 1; if (s[mid] < k) lo = mid+1; else hi = mid; }
      rank += lo;
    }
    unsigned se = ~((unsigned)(k >> 22));
    unsigned info = (unsigned)j | ((unsigned)lvl << 10) | ((se != S_NEGINF) ? (1u<<13) : 0u);
    rankinfo[(size_t)n*K_SEL + rank] = info;   // exact permutation of [0,5000)
  }
}

// ---------------- K6a: suppression bit-matrix, ballot + column layout, 4 waves/block ----------------
__global__ __launch_bounds__(256) void k_ioumat_lvl(const float4* lobox, const float* loarea, unsigned* lmat){
  int grp = blockIdx.y;                  // n*5 + L
  int wblk = blockIdx.x;                 // j-block: j = wblk*64 + lane
  int tid = threadIdx.x;
  int lane = tid & 63, q = tid >> 6;
  __shared__ float sx1[PRE], sy1[PRE], sx2[PRE], sy2[PRE], sar[PRE];
  for (int i = tid; i < PRE; i += 256){
    float4 bb = lobox[(size_t)grp*PRE + i];
    sx1[i]=bb.x; sy1[i]=bb.y; sx2[i]=bb.z; sy2[i]=bb.w;
    sar[i]=loarea[(size_t)grp*PRE + i];
  }
  __syncthreads();
  int j = wblk*64 + lane;
  float jx1=0.f,jy1=0.f,jx2=0.f,jy2=0.f,ja=0.f;
  if (j < PRE){
    float4 bb = lobox[(size_t)grp*PRE + j];
    jx1=bb.x; jy1=bb.y; jx2=bb.z; jy2=bb.w; ja=loarea[(size_t)grp*PRE + j];
  }
  unsigned* mg = lmat + (size_t)grp*GRPW + (size_t)wblk*2*PRE;
  int pmax = min(PRE, wblk*64 + 63);     // rows p >= pmax: no j>p in this block
  int q0 = q*250, q1 = q0 + 250;
  int pm = min(q1, pmax);

#define IOU_HIT(P, OUT) { \
    float bx1=sx1[P], by1=sy1[P], bx2=sx2[P], by2=sy2[P], ba=sar[P]; \
    float ltx = fmaxf(bx1, jx1), lty = fmaxf(by1, jy1); \
    float rbx = fminf(bx2, jx2), rby = fminf(by2, jy2); \
    float ww = fmaxf(__fsub_rn(rbx,ltx), 0.0f); \
    float hh = fmaxf(__fsub_rn(rby,lty), 0.0f); \
    float inter = __fmul_rn(ww,hh); \
    float uni = __fsub_rn(__fadd_rn(ba, ja), inter); \
    OUT = (__fdiv_rn(inter,uni) > 0.7f) && (j > (P)) && (j < PRE); }

  int p = q0;
  for (; p + 4 <= pm; p += 4){
    bool h0,h1,h2,h3;
    IOU_HIT(p,   h0);
    IOU_HIT(p+1, h1);
    IOU_HIT(p+2, h2);
    IOU_HIT(p+3, h3);
    unsigned long long b0 = __ballot(h0), b1 = __ballot(h1);
    unsigned long long b2 = __ballot(h2), b3 = __ballot(h3);
    if ((lane & 31) == 0){
      int d = lane >> 5;
      mg[(p  )*2 + d] = (lane==0) ? (unsigned)b0 : (unsigned)(b0>>32);
      mg[(p+1)*2 + d] = (lane==0) ? (unsigned)b1 : (unsigned)(b1>>32);
      mg[(p+2)*2 + d] = (lane==0) ? (unsigned)b2 : (unsigned)(b2>>32);
      mg[(p+3)*2 + d] = (lane==0) ? (unsigned)b3 : (unsigned)(b3>>32);
    }
  }
  for (; p < pm; ++p){
    bool h; IOU_HIT(p, h);
    unsigned long long bal = __ballot(h);
    if ((lane & 31) == 0)
      mg[p*2 + (lane>>5)] = (lane==0) ? (unsigned)bal : (unsigned)(bal>>32);
  }
#undef IOU_HIT
  int zs = (pm > q0 ? pm : q0);
  for (int w = zs*2 + lane; w < q1*2; w += 64) mg[w] = 0u;   // contiguous zero-fill
}

// ---------------- K6b: tile-parallel greedy scan, latency-batched TPROC ----------------
__global__ __launch_bounds__(64) void k_scan_nms5(const unsigned* rankinfo, const unsigned* lmat,
                                                  const float4* lbox, const float* lskey, float* out){
  __shared__ unsigned lrows[64][36];     // row-major tile; stride 36 words
  __shared__ unsigned lsup[160];         // 5 levels x 32 words suppression state
  int n = blockIdx.x; int lane = threadIdx.x;
  int n5 = n*5;
  const unsigned* rin = rankinfo + (size_t)n*K_SEL;
  float* outn = out + (size_t)n*PRE*5;
  for (int i = lane; i < PRE*5; i += 64) outn[i] = 0.0f;   // own-image zero (replaces memset)
  for (int i = lane; i < 160; i += 64) lsup[i] = 0u;
  int kept_total = 0;
  uint2 Pa,Pb,Pc,Pd,Pe,Pf,Pg,Ph,Pi,Pj,Pk,Pl,Pm,Pn,Po,Pp;  // 16x8B staging
  float4 boxP; float scP = 0.f;
  unsigned infoC, infoN;
  int rgrp = lane >> 4;                  // 0..3: row subgroup
  unsigned wboff = (unsigned)(lane & 15) * (2u*PRE);  // my wblk's column segment
  int wb2 = (lane & 15) << 1;            // word index within row

#define SLOAD(INFO) { \
    unsigned L_ = ((INFO)>>10)&7u; unsigned p_ = (INFO) & 1023u; \
    unsigned rowu_ = ((unsigned)n5 + L_)*GRPW + p_*2u; \
    unsigned rb_; \
    rb_ = __shfl(rowu_,  0 + rgrp); Pa = *(const uint2*)(lmat + rb_ + wboff); \
    rb_ = __shfl(rowu_,  4 + rgrp); Pb = *(const uint2*)(lmat + rb_ + wboff); \
    rb_ = __shfl(rowu_,  8 + rgrp); Pc = *(const uint2*)(lmat + rb_ + wboff); \
    rb_ = __shfl(rowu_, 12 + rgrp); Pd = *(const uint2*)(lmat + rb_ + wboff); \
    rb_ = __shfl(rowu_, 16 + rgrp); Pe = *(const uint2*)(lmat + rb_ + wboff); \
    rb_ = __shfl(rowu_, 20 + rgrp); Pf = *(const uint2*)(lmat + rb_ + wboff); \
    rb_ = __shfl(rowu_, 24 + rgrp); Pg = *(const uint2*)(lmat + rb_ + wboff); \
    rb_ = __shfl(rowu_, 28 + rgrp); Ph = *(const uint2*)(lmat + rb_ + wboff); \
    rb_ = __shfl(rowu_, 32 + rgrp); Pi = *(const uint2*)(lmat + rb_ + wboff); \
    rb_ = __shfl(rowu_, 36 + rgrp); Pj = *(const uint2*)(lmat + rb_ + wboff); \
    rb_ = __shfl(rowu_, 40 + rgrp); Pk = *(const uint2*)(lmat + rb_ + wboff); \
    rb_ = __shfl(rowu_, 44 + rgrp); Pl = *(const uint2*)(lmat + rb_ + wboff); \
    rb_ = __shfl(rowu_, 48 + rgrp); Pm = *(const uint2*)(lmat + rb_ + wboff); \
    rb_ = __shfl(rowu_, 52 + rgrp); Pn = *(const uint2*)(lmat + rb_ + wboff); \
    rb_ = __shfl(rowu_, 56 + rgrp); Po = *(const uint2*)(lmat + rb_ + wboff); \
    rb_ = __shfl(rowu_, 60 + rgrp); Pp = *(const uint2*)(lmat + rb_ + wboff); \
    size_t bi_ = (size_t)((unsigned)n5 + L_)*PRE + p_; \
    boxP = lbox[bi_]; scP = lskey[bi_]; }

#define SWRITE() { \
    *(uint2*)&lrows[ 0 + rgrp][wb2] = Pa; *(uint2*)&lrows[ 4 + rgrp][wb2] = Pb; \
    *(uint2*)&lrows[ 8 + rgrp][wb2] = Pc; *(uint2*)&lrows[12 + rgrp][wb2] = Pd; \
    *(uint2*)&lrows[16 + rgrp][wb2] = Pe; *(uint2*)&lrows[20 + rgrp][wb2] = Pf; \
    *(uint2*)&lrows[24 + rgrp][wb2] = Pg; *(uint2*)&lrows[28 + rgrp][wb2] = Ph; \
    *(uint2*)&lrows[32 + rgrp][wb2] = Pi; *(uint2*)&lrows[36 + rgrp][wb2] = Pj; \
    *(uint2*)&lrows[40 + rgrp][wb2] = Pk; *(uint2*)&lrows[44 + rgrp][wb2] = Pl; \
    *(uint2*)&lrows[48 + rgrp][wb2] = Pm; *(uint2*)&lrows[52 + rgrp][wb2] = Pn; \
    *(uint2*)&lrows[56 + rgrp][wb2] = Po; *(uint2*)&lrows[60 + rgrp][wb2] = Pp; }

#define GRP16(B, ACC, SH) { \
    unsigned q0_=lrows[(B)+ 0][idxw_], q1_=lrows[(B)+ 1][idxw_], \
             q2_=lrows[(B)+ 2][idxw_], q3_=lrows[(B)+ 3][idxw_], \
             q4_=lrows[(B)+ 4][idxw_], q5_=lrows[(B)+ 5][idxw_], \
             q6_=lrows[(B)+ 6][idxw_], q7_=lrows[(B)+ 7][idxw_], \
             q8_=lrows[(B)+ 8][idxw_], q9_=lrows[(B)+ 9][idxw_], \
             qa_=lrows[(B)+10][idxw_], qb_=lrows[(B)+11][idxw_], \
             qc_=lrows[(B)+12][idxw_], qd_=lrows[(B)+13][idxw_], \
             qe_=lrows[(B)+14][idxw_], qf_=lrows[(B)+15][idxw_]; \
    ACC |= (((q0_>>pb_)&1u)<<((SH)+ 0)) | (((q1_>>pb_)&1u)<<((SH)+ 1)) \
         | (((q2_>>pb_)&1u)<<((SH)+ 2)) | (((q3_>>pb_)&1u)<<((SH)+ 3)) \
         | (((q4_>>pb_)&1u)<<((SH)+ 4)) | (((q5_>>pb_)&1u)<<((SH)+ 5)) \
         | (((q6_>>pb_)&1u)<<((SH)+ 6)) | (((q7_>>pb_)&1u)<<((SH)+ 7)) \
         | (((q8_>>pb_)&1u)<<((SH)+ 8)) | (((q9_>>pb_)&1u)<<((SH)+ 9)) \
         | (((qa_>>pb_)&1u)<<((SH)+10)) | (((qb_>>pb_)&1u)<<((SH)+11)) \
         | (((qc_>>pb_)&1u)<<((SH)+12)) | (((qd_>>pb_)&1u)<<((SH)+13)) \
         | (((qe_>>pb_)&1u)<<((SH)+14)) | (((qf_>>pb_)&1u)<<((SH)+15)); }

#define TPROC(INFO, BOX, SC, baseexpr) { \
    int base_ = (baseexpr); \
    unsigned L_ = ((INFO)>>10)&7u; unsigned p_ = (INFO) & 1023u; \
    int idxw_ = (int)(p_ >> 5); unsigned pb_ = p_ & 31u; \
    unsigned long long lb0_=__ballot(L_==0u), lb1_=__ballot(L_==1u), \
                       lb2_=__ballot(L_==2u), lb3_=__ballot(L_==3u), lb4_=__ballot(L_==4u); \
    unsigned long long myLvl_ = (L_==0u)?lb0_:(L_==1u)?lb1_:(L_==2u)?lb2_:(L_==3u)?lb3_:lb4_; \
    unsigned sw_ = lsup[L_*32u + (unsigned)idxw_]; \
    bool ok_ = ((((INFO)>>13)&1u)!=0u) && (base_ + lane < K_SEL) && (((sw_>>pb_)&1u)==0u); \
    unsigned long long cand_ = __ballot(ok_); \
    unsigned alo_ = 0u, ahi_ = 0u; \
    GRP16( 0, alo_,  0); GRP16(16, alo_, 16); \
    GRP16(32, ahi_,  0); GRP16(48, ahi_, 16); \
    unsigned long long cm_ = ((((unsigned long long)ahi_)<<32)|(unsigned long long)alo_) & myLvl_; \
    unsigned long long keptM_ = 0ull; \
    while (cand_){ \
      bool safe_ = (((cand_>>lane)&1ull)!=0ull) && ((cm_ & cand_)==0ull); \
      unsigned long long nk_ = __ballot(safe_); \
      keptM_ |= nk_; \
      bool dead_ = (((cand_>>lane)&1ull)!=0ull) && ((cm_ & nk_)!=0ull); \
      cand_ &= ~(nk_ | __ballot(dead_)); \
    } \
    if (((keptM_>>lane)&1ull)!=0ull){ \
      unsigned sb_ = L_*32u; \
      _Pragma("unroll") \
      for (int k_ = 0; k_ < 32; ++k_){ \
        unsigned w_ = (unsigned)((k_+lane)&31); \
        atomicOr(&lsup[sb_+w_], lrows[lane][w_]); \
      } \
    } \
    int pos_ = kept_total + (int)__popcll(keptM_ & ((1ull<<lane)-1ull)); \
    if ((((keptM_>>lane)&1ull)!=0ull) && pos_ < PRE){ \
      float* orow_ = outn + (size_t)pos_*5; \
      orow_[0]=(BOX).x; orow_[1]=(BOX).y; orow_[2]=(BOX).z; orow_[3]=(BOX).w; orow_[4]=(SC); \
    } \
    kept_total += (int)__popcll(keptM_); \
    asm volatile("s_waitcnt lgkmcnt(0)" ::: "memory"); \
  }

  infoC = rin[lane];
  SLOAD(infoC);                          // tile 0 rows -> regs, box -> boxP
  SWRITE();                              // tile 0 rows -> LDS
  float4 boxC = boxP; float scC = scP;
  infoN = rin[64 + lane];

  for (int t = 0; t < TILES; ++t){
    if (t+1 < TILES) SLOAD(infoN);       // issue next tile's loads (rows + box)
    asm volatile("s_waitcnt lgkmcnt(0)" ::: "memory");   // lrows writes visible
    TPROC(infoC, boxC, scC, t*64);
    if (kept_total >= PRE) break;
    if (t+1 < TILES){
      SWRITE();                          // waits next tile's loads (covered by TPROC)
      boxC = boxP; scC = scP;
      infoC = infoN;
      if (t+2 < TILES){
        int nx = (t+2)*64 + lane; if (nx > K_SEL-1) nx = K_SEL-1;
        infoN = rin[nx];
      }
    }
  }
#undef SLOAD
#undef SWRITE
#undef GRP16
#undef TPROC
}

// ---------------- fallback path (ws too small): round-3 kernels ----------------
__global__ __launch_bounds__(256) void k_sortimg(const unsigned long long* keys,
                                                 const float* d0,const float* d1,const float* d2,const float* d3,const float* d4,
                                                 const float* anchors,
                                                 float4* sbox, float* sskey, int* slvl){
  int n = blockIdx.x;
  __shared__ unsigned long long sk[8192];
  for (int i = threadIdx.x; i < 8192; i += 256)
    sk[i] = (i < K_SEL) ? keys[(size_t)n*K_SEL + i] : ~0ULL;
  __syncthreads();
  bitonic<8192>(sk);
  for (int r = threadIdx.x; r < K_SEL; r += 256){
    unsigned long long key = sk[r];
    int t = (int)(key & 0x7FFFFu);
    int lvl = (int)((key >> 19) & 7u);
    unsigned se = ~((unsigned)(key >> 22));
    const float* dl = sel5(lvl,d0,d1,d2,d3,d4);
    BoxV b = decode_box(lvl, t, n, dl, anchors);
    sbox[(size_t)n*K_SEL + r] = make_float4(b.x1,b.y1,b.x2,b.y2);
    sskey[(size_t)n*K_SEL + r] = s2f(se);
    slvl[(size_t)n*K_SEL + r] = lvl;
  }
}

__global__ __launch_bounds__(256) void k_nms(const float4* sbox, const float* sskey, const int* slvl, float* out){
  int n = blockIdx.x, tid = threadIdx.x;
  __shared__ float kx1[PRE], ky1[PRE], kx2[PRE], ky2[PRE], kar[PRE];
  __shared__ int klv[PRE];
  __shared__ int nv_s, flag_s;
  for (int i = tid; i < PRE*5; i += 256) out[(size_t)n*PRE*5 + i] = 0.0f;
  if (tid == 0){ nv_s = 0; flag_s = 0; }
  __syncthreads();
  int c = 0;
  for (int i = tid; i < K_SEL; i += 256)
    if (sskey[(size_t)n*K_SEL + i] != -INFINITY) ++c;
  atomicAdd(&nv_s, c);
  __syncthreads();
  int nvalid = nv_s;
  int kept = 0;
  for (int i = 0; i < nvalid; ++i){
    float4 b = sbox[(size_t)n*K_SEL + i];
    int lv = slvl[(size_t)n*K_SEL + i];
    float off = (float)lv * 1345.0f;
    float ox1 = __fadd_rn(b.x, off), oy1 = __fadd_rn(b.y, off);
    float ox2 = __fadd_rn(b.z, off), oy2 = __fadd_rn(b.w, off);
    float area = __fmul_rn(__fsub_rn(ox2,ox1), __fsub_rn(oy2,oy1));
    bool hit = false;
    for (int j = tid; j < kept; j += 256){
      if (klv[j] == lv){
        float ltx = fmaxf(kx1[j], ox1), lty = fmaxf(ky1[j], oy1);
        float rbx = fminf(kx2[j], ox2), rby = fminf(ky2[j], oy2);
        float w = fmaxf(__fsub_rn(rbx,ltx), 0.0f);
        float h = fmaxf(__fsub_rn(rby,lty), 0.0f);
        float inter = __fmul_rn(w,h);
        float uni = __fsub_rn(__fadd_rn(kar[j], area), inter);
        if (__fdiv_rn(inter,uni) > 0.7f) hit = true;
      }
    }
    if (hit) flag_s = 1;
    __syncthreads();
    int sup = flag_s;
    __syncthreads();
    if (!sup){
      if (tid == 0){
        kx1[kept]=ox1; ky1[kept]=oy1; kx2[kept]=ox2; ky2[kept]=oy2; kar[kept]=area; klv[kept]=lv;
        float* orow = out + (size_t)n*PRE*5 + (size_t)kept*5;
        orow[0]=b.x; orow[1]=b.y; orow[2]=b.z; orow[3]=b.w;
        orow[4]=sskey[(size_t)n*K_SEL + i];
      }
      ++kept;
    }
    if (tid == 0) flag_s = 0;
    __syncthreads();
    if (kept == PRE) break;
  }
}

extern "C" void kernel_launch(void* const* d_in, const int* in_sizes, int n_in,
                              void* d_out, int out_size, void* d_ws, size_t ws_size,
                              hipStream_t stream) {
  bool interleaved = (in_sizes[1] == 4*in_sizes[0]);
  const float* obj[5]; const float* dlt[5];
  for (int i = 0; i < 5; ++i){
    if (interleaved){ obj[i] = (const float*)d_in[2*i]; dlt[i] = (const float*)d_in[2*i+1]; }
    else            { obj[i] = (const float*)d_in[i];   dlt[i] = (const float*)d_in[5+i]; }
  }
  const float* anchors = (const float*)d_in[10];

  char* ws = (char*)d_ws;
  unsigned* hist            = (unsigned*)(ws);                     // 655360
  unsigned* cnt_gt          = (unsigned*)(ws + 655360);            // 160
  unsigned* cnt_eq          = (unsigned*)(ws + 655520);            // 160
  unsigned* thi             = (unsigned*)(ws + 655680);            // 160 -> counters end 655840
  unsigned long long* cand  = (unsigned long long*)(ws + 655840);  // 1310720 -> 1966560
  unsigned long long* keys  = (unsigned long long*)(ws + 1966560); // 320000 -> 2286560
  float4* lbox              = (float4*)(ws + 2286560);             // 640000 -> 2926560
  float4* lobox             = (float4*)(ws + 2926560);             // 640000 -> 3566560
  float* loarea             = (float*)(ws + 3566560);              // 160000 -> 3726560
  float* lskey              = (float*)(ws + 3726560);              // 160000 -> 3886560
  unsigned* rankinfo        = (unsigned*)(ws + 3886560);           // 160000 -> 4046560
  unsigned* lmat            = (unsigned*)(ws + 4046560);           // 5120000 -> 9166560
  float4* sbox              = (float4*)(ws + 9166560);             // fallback: 640000 -> 9806560
  float* sskey              = (float*)(ws + 9806560);              // 160000 -> 9966560
  int* slvl                 = (int*)(ws + 9966560);                // 160000 -> 10126560
  const size_t NEED = 10126560;

  hipMemsetAsync(ws, 0, 655840, stream);   // hist + counters

  dim3 gChunk(42, 40);                   // 42 chunks x 8192 covers level-0's 338688
  k_hist<<<gChunk, 256, 0, stream>>>(obj[0],obj[1],obj[2],obj[3],obj[4], hist);
  k_scan<<<40, 256, 0, stream>>>(hist, thi);
  k_compact<<<gChunk, 256, 0, stream>>>(obj[0],obj[1],obj[2],obj[3],obj[4],
                                        dlt[0],dlt[1],dlt[2],dlt[3],dlt[4],
                                        anchors, thi, cnt_gt, cnt_eq, cand, keys);
  k_tiesel<<<dim3(16, 40), 256, 0, stream>>>(dlt[0],dlt[1],dlt[2],dlt[3],dlt[4], anchors,
                                             cnt_gt, cnt_eq, cand, keys);
  if (ws_size >= NEED){
    k_sortlvl<<<40, 256, 0, stream>>>(keys);
    k_declvl<<<dim3(8, 40), 256, 0, stream>>>(keys, dlt[0],dlt[1],dlt[2],dlt[3],dlt[4], anchors,
                                              lbox, lobox, loarea, lskey);
    k_rank<<<40, 256, 0, stream>>>(keys, rankinfo);
    k_ioumat_lvl<<<dim3(16, 40), 256, 0, stream>>>(lobox, loarea, lmat);
    k_scan_nms5<<<8, 64, 0, stream>>>(rankinfo, lmat, lbox, lskey, (float*)d_out);
  } else {
    k_sortimg<<<8, 256, 0, stream>>>(keys, dlt[0],dlt[1],dlt[2],dlt[3],dlt[4], anchors,
                                     sbox, sskey, slvl);
    k_nms<<<8, 256, 0, stream>>>(sbox, sskey, slvl, (float*)d_out);
  }
}

// Round 17
// 207.832 us; speedup vs baseline: 1.3822x; 1.0639x over previous
//
#include <hip/hip_runtime.h>
#include <cmath>

#define N_IMG   8
#define PRE     1000
#define K_SEL   5000
#define NBIN    4096
#define TIE_CAP 4096
#define IMG_F   1344.0f
#define S_NEGINF 0x007FFFFFu
#define TILES   79             // ceil(5000/64)
#define GRPW    32000          // words per grp in lmat: 16 wblk x 1000 p x 2
#define CHUNK   8192           // elements per block in k_hist/k_compact

__constant__ int c_W[5]   = {336,168,84,42,21};
__constant__ int c_HW[5]  = {112896,28224,7056,1764,441};
__constant__ int c_OFF[5] = {0,338688,423360,444528,449820};

__device__ __forceinline__ unsigned f2s(float f){
  unsigned u = __float_as_uint(f);
  return (u & 0x80000000u) ? ~u : (u | 0x80000000u);
}
__device__ __forceinline__ float s2f(unsigned s){
  unsigned u = (s & 0x80000000u) ? (s & 0x7FFFFFFFu) : ~s;
  return __uint_as_float(u);
}
__device__ __forceinline__ const float* sel5(int l, const float* p0,const float* p1,const float* p2,const float* p3,const float* p4){
  switch(l){case 0:return p0;case 1:return p1;case 2:return p2;case 3:return p3;default:return p4;}
}

struct BoxV { float x1,y1,x2,y2; bool valid; };

// Bit-faithful torchvision BoxCoder.decode + clip + min-size validity.
__device__ BoxV decode_box(int lvl, int t, int n, const float* dl, const float* anchors){
  int HW = c_HW[lvl], W = c_W[lvl];
  int a = t % 3, pos = t / 3;          // t = (h*W+w)*3 + a
  int h = pos / W, w = pos - h*W;
  int g = c_OFF[lvl] + t;
  const float* an = anchors + (size_t)4*(size_t)g;
  float a0=an[0], a1=an[1], a2=an[2], a3=an[3];
  float aw = __fsub_rn(a2,a0), ah = __fsub_rn(a3,a1);
  float acx = __fadd_rn(a0, __fmul_rn(0.5f,aw));
  float acy = __fadd_rn(a1, __fmul_rn(0.5f,ah));
  const float* dp = dl + ((size_t)n*12 + (size_t)a*4)*(size_t)HW + (size_t)h*W + (size_t)w;
  float dx = dp[0], dy = dp[HW], dwv = dp[2*(size_t)HW], dhv = dp[3*(size_t)HW];
  const float CLAMP = (float)4.135166556742356;  // log(1000/16)
  dwv = fminf(dwv, CLAMP); dhv = fminf(dhv, CLAMP);
  float pcx = __fadd_rn(__fmul_rn(dx,aw), acx);
  float pcy = __fadd_rn(__fmul_rn(dy,ah), acy);
  float pw = __fmul_rn((float)::exp((double)dwv), aw);
  float ph = __fmul_rn((float)::exp((double)dhv), ah);
  float hx = __fmul_rn(0.5f,pw), hy = __fmul_rn(0.5f,ph);
  BoxV b;
  b.x1 = fminf(fmaxf(__fsub_rn(pcx,hx),0.0f),IMG_F);
  b.y1 = fminf(fmaxf(__fsub_rn(pcy,hy),0.0f),IMG_F);
  b.x2 = fminf(fmaxf(__fadd_rn(pcx,hx),0.0f),IMG_F);
  b.y2 = fminf(fmaxf(__fadd_rn(pcy,hy),0.0f),IMG_F);
  b.valid = (__fsub_rn(b.x2,b.x1) >= 1e-3f) && (__fsub_rn(b.y2,b.y1) >= 1e-3f);
  return b;
}

// key = (~s_eff)<<22 | lvl<<19 | t : ascending sort == (score desc, level asc, idx asc)
__device__ unsigned long long make_key(unsigned s, int lvl, int t, int n, const float* dl, const float* anchors){
  BoxV b = decode_box(lvl,t,n,dl,anchors);
  unsigned se = b.valid ? s : S_NEGINF;     // invalid -> skey = -inf
  return ((unsigned long long)(~se) << 22) | ((unsigned long long)(unsigned)lvl << 19) | (unsigned long long)(unsigned)t;
}

// ---------------- K1: per-(image,level) 12-bit score histogram (chunked grid) ----------------
__global__ __launch_bounds__(256) void k_hist(const float* o0,const float* o1,const float* o2,const float* o3,const float* o4,
                                              unsigned* hist){
  int grp = blockIdx.y; int n = grp/5, lvl = grp - n*5;
  int HW = c_HW[lvl], M = 3*HW;
  int base = blockIdx.x * CHUNK;
  if (base >= M) return;                 // idle block for short levels
  int end = min(base + CHUNK, M);
  const float* ob = sel5(lvl,o0,o1,o2,o3,o4) + (size_t)n*(size_t)M;
  __shared__ unsigned lh[NBIN];
  for (int b = threadIdx.x; b < NBIN; b += 256) lh[b] = 0;
  __syncthreads();
  for (int i = base + threadIdx.x; i < end; i += 256){
    unsigned s = f2s(ob[i]);
    atomicAdd(&lh[s >> 20], 1u);
  }
  __syncthreads();
  unsigned* gh = hist + (size_t)grp*NBIN;
  for (int b = threadIdx.x; b < NBIN; b += 256){ unsigned v = lh[b]; if (v) atomicAdd(&gh[b], v); }
}

// ---------------- K2: find bin containing the 1000th-largest score ----------------
__global__ __launch_bounds__(256) void k_scan(const unsigned* hist, unsigned* thi){
  int grp = blockIdx.x;
  const unsigned* gh = hist + (size_t)grp*NBIN;
  __shared__ unsigned part[256];
  unsigned ssum = 0;
  int base = threadIdx.x*16;
  for (int b = base; b < base+16; ++b) ssum += gh[b];
  part[threadIdx.x] = ssum;
  __syncthreads();
  if (threadIdx.x == 0){
    int k = PRE;
    int c = 255;
    while ((int)part[c] < k){ k -= (int)part[c]; --c; }
    int b = c*16 + 15;
    while ((int)gh[b] < k){ k -= (int)gh[b]; --b; }
    thi[grp] = (unsigned)b;
  }
}

// ---------------- K3: compact >bin elements (two-phase: LDS lists + block reservation) ----------------
__global__ __launch_bounds__(256) void k_compact(const float* o0,const float* o1,const float* o2,const float* o3,const float* o4,
                                                 const float* d0,const float* d1,const float* d2,const float* d3,const float* d4,
                                                 const float* anchors, const unsigned* thi,
                                                 unsigned* cnt_gt, unsigned* cnt_eq,
                                                 unsigned long long* cand, unsigned long long* keys){
  int grp = blockIdx.y; int n = grp/5, lvl = grp - n*5;
  int HW = c_HW[lvl], M = 3*HW;
  int base = blockIdx.x * CHUNK;
  if (base >= M) return;
  int end = min(base + CHUNK, M);
  const float* ob = sel5(lvl,o0,o1,o2,o3,o4) + (size_t)n*(size_t)M;
  const float* dl = sel5(lvl,d0,d1,d2,d3,d4);
  unsigned T = thi[grp];
  __shared__ int lgt[1024];              // per-group gt total < 1000 -> block gt <= 999
  __shared__ int leq[TIE_CAP];
  __shared__ unsigned cgt_s, ceq_s, bgt_s, beq_s;
  if (threadIdx.x == 0){ cgt_s = 0u; ceq_s = 0u; }
  __syncthreads();
  for (int i = base + threadIdx.x; i < end; i += 256){
    unsigned s = f2s(ob[i]);
    unsigned sh = s >> 20;
    if (sh > T){
      unsigned k = atomicAdd(&cgt_s, 1u);
      if (k < 1024u) lgt[k] = i;
    } else if (sh == T){
      unsigned k = atomicAdd(&ceq_s, 1u);
      if (k < (unsigned)TIE_CAP) leq[k] = i;
    }
  }
  __syncthreads();
  if (threadIdx.x == 0){
    bgt_s = atomicAdd(&cnt_gt[grp], min(cgt_s, 1024u));
    beq_s = atomicAdd(&cnt_eq[grp], min(ceq_s, (unsigned)TIE_CAP));
  }
  __syncthreads();
  unsigned cg = min(cgt_s, 1024u), ce = min(ceq_s, (unsigned)TIE_CAP);
  unsigned bgt = bgt_s, beq = beq_s;
  unsigned long long* kout = keys + (size_t)n*K_SEL + (size_t)lvl*PRE;
  for (unsigned k = threadIdx.x; k < cg; k += 256){
    int i = lgt[k];
    unsigned s = f2s(ob[i]);
    int a = i / HW; int rem = i - a*HW; int t = rem*3 + a;
    kout[bgt + k] = make_key(s, lvl, t, n, dl, anchors);
  }
  for (unsigned k = threadIdx.x; k < ce; k += 256){
    unsigned e = beq + k;
    if (e < (unsigned)TIE_CAP){
      int i = leq[k];
      unsigned s = f2s(ob[i]);
      int a = i / HW; int rem = i - a*HW; int t = rem*3 + a;
      cand[(size_t)grp*TIE_CAP + e] = ((unsigned long long)(~s) << 19) | (unsigned long long)(unsigned)t;
    }
  }
}

template<int SZ>
__device__ void bitonic(unsigned long long* sk){
  for (int k = 2; k <= SZ; k <<= 1){
    for (int j = k >> 1; j > 0; j >>= 1){
      for (int i = threadIdx.x; i < SZ; i += blockDim.x){
        int ix = i ^ j;
        if (ix > i){
          unsigned long long va = sk[i], vb = sk[ix];
          if ((va > vb) == ((i & k) == 0)){ sk[i] = vb; sk[ix] = va; }
        }
      }
      __syncthreads();
    }
  }
}

// ---------------- K4: boundary selection via rank-select, 16 runtime chunks/group ----------------
__global__ __launch_bounds__(256) void k_tiesel(const float* d0,const float* d1,const float* d2,const float* d3,const float* d4,
                                                const float* anchors,
                                                const unsigned* cnt_gt, const unsigned* cnt_eq,
                                                const unsigned long long* cand, unsigned long long* keys){
  int grp = blockIdx.y; int n = grp/5, lvl = grp - n*5;
  int q = blockIdx.x;                    // 16 runtime chunks
  __shared__ unsigned long long sk[TIE_CAP];
  int ne = min((int)cnt_eq[grp], TIE_CAP);
  int cg = (int)cnt_gt[grp];
  int need = PRE - cg;
  const float* dl = sel5(lvl,d0,d1,d2,d3,d4);
  unsigned long long* kout = keys + (size_t)n*K_SEL + (size_t)lvl*PRE + cg;
  if (q == 0){  // pathological overflow pad (ne < need): harmless invalid keys
    for (int j = ne + threadIdx.x; j < need; j += 256)
      kout[j] = ((unsigned long long)(~S_NEGINF) << 22);
  }
  int chunk = (ne + 15) >> 4;
  int c0 = q*chunk, c1 = min(ne, c0 + chunk);
  if (c0 >= ne) return;
  for (int i = threadIdx.x; i < ne; i += 256)
    sk[i] = cand[(size_t)grp*TIE_CAP + i];
  __syncthreads();
  for (int c = c0 + threadIdx.x; c < c1; c += 256){
    unsigned long long ck = sk[c];
    int rank = 0;
    int i = 0;
    for (; i + 8 <= ne; i += 8){
      rank += (int)(sk[i  ] < ck) + (int)(sk[i+1] < ck)
            + (int)(sk[i+2] < ck) + (int)(sk[i+3] < ck)
            + (int)(sk[i+4] < ck) + (int)(sk[i+5] < ck)
            + (int)(sk[i+6] < ck) + (int)(sk[i+7] < ck);
    }
    for (; i < ne; ++i) rank += (int)(sk[i] < ck);
    if (rank < need){
      unsigned t = (unsigned)(ck & 0x7FFFFu);
      unsigned s = ~((unsigned)(ck >> 19));
      kout[rank] = make_key(s, lvl, (int)t, n, dl, anchors);
    }
  }
}

// ---------------- K5a: sort each (image,level) run (sort only; decode split out) ----------------
__global__ __launch_bounds__(256) void k_sortlvl(unsigned long long* keys){
  int grp = blockIdx.x; int n = grp/5, lvl = grp - n*5;
  __shared__ unsigned long long sk[1024];
  unsigned long long* kp = keys + (size_t)n*K_SEL + (size_t)lvl*PRE;
  for (int i = threadIdx.x; i < 1024; i += 256)
    sk[i] = (i < PRE) ? kp[i] : ~0ULL;
  __syncthreads();
  bitonic<1024>(sk);
  for (int i = threadIdx.x; i < PRE; i += 256) kp[i] = sk[i];
}

// ---------------- K5a2: decode sorted keys -> level-space arrays, 8 blocks/group ----------------
__global__ __launch_bounds__(256) void k_declvl(const unsigned long long* keys,
                                                const float* d0,const float* d1,const float* d2,const float* d3,const float* d4,
                                                const float* anchors,
                                                float4* lbox, float4* lobox, float* loarea, float* lskey){
  int grp = blockIdx.y; int n = grp/5, lvl = grp - n*5;
  if (threadIdx.x >= 125) return;
  int i = blockIdx.x*125 + threadIdx.x;  // 8 x 125 = 1000
  unsigned long long key = keys[(size_t)n*K_SEL + (size_t)lvl*PRE + i];
  int t = (int)(key & 0x7FFFFu);
  unsigned se = ~((unsigned)(key >> 22));
  const float* dl = sel5(lvl,d0,d1,d2,d3,d4);
  BoxV b = decode_box(lvl, t, n, dl, anchors);
  size_t o = (size_t)grp*PRE + i;
  lbox[o] = make_float4(b.x1,b.y1,b.x2,b.y2);
  lskey[o] = s2f(se);                   // -inf if invalid
  float off = (float)lvl * 1345.0f;     // (IMG+1) batched-NMS offset
  float ox1 = __fadd_rn(b.x1, off), oy1 = __fadd_rn(b.y1, off);
  float ox2 = __fadd_rn(b.x2, off), oy2 = __fadd_rn(b.y2, off);
  lobox[o] = make_float4(ox1,oy1,ox2,oy2);
  loarea[o] = __fmul_rn(__fsub_rn(ox2,ox1), __fsub_rn(oy2,oy1));
}

// ---------------- K5b: global rank, one block per (image, level) ----------------
// rankinfo[rank] = p | (lvl<<10) | (valid<<13)
__global__ __launch_bounds__(256) void k_rank(const unsigned long long* keys, unsigned* rankinfo){
  int grp5 = blockIdx.x;                 // n*5 + lvl
  int n = grp5/5, lvl = grp5 - n*5;
  __shared__ unsigned long long sl[K_SEL];
  for (int i = threadIdx.x; i < K_SEL; i += 256) sl[i] = keys[(size_t)n*K_SEL + i];
  __syncthreads();
  for (int j = threadIdx.x; j < PRE; j += 256){
    unsigned long long k = sl[lvl*PRE + j];
    int rank = j;
    #pragma unroll
    for (int m = 0; m < 5; ++m){
      if (m == lvl) continue;
      const unsigned long long* s = sl + m*PRE;
      int lo = 0, hi = PRE;
      while (lo < hi){ int mid = (lo+hi) >> 1; if (s[mid] < k) lo = mid+1; else hi = mid; }
      rank += lo;
    }
    unsigned se = ~((unsigned)(k >> 22));
    unsigned info = (unsigned)j | ((unsigned)lvl << 10) | ((se != S_NEGINF) ? (1u<<13) : 0u);
    rankinfo[(size_t)n*K_SEL + rank] = info;   // exact permutation of [0,5000)
  }
}

// ---------------- K6a: suppression bit-matrix, 1 wave per (wblk, 125-row p-chunk) ----------------
// Round-16 lesson: 4-wave blocks stage 1000 boxes and triangle-idle 3 waves; long
// tail = 250 latency-chained iters at 10% occupancy. Now: grid (16*8, 40) = 5120
// waves, each stages <=125 boxes (2.5KB LDS), <=125 iters. Same op order -> bit-exact.
__global__ __launch_bounds__(64) void k_ioumat_lvl(const float4* lobox, const float* loarea, unsigned* lmat){
  int grp = blockIdx.y;                  // n*5 + L
  int bx = blockIdx.x;
  int wblk = bx >> 3;                    // 0..15: j-block (j = wblk*64 + lane)
  int pc   = bx & 7;                     // 0..7: p-chunk of 125
  int lane = threadIdx.x;
  int p0 = pc*125, p1 = p0 + 125;
  unsigned* mg = lmat + (size_t)grp*GRPW + (size_t)wblk*2*PRE;
  int pmax = min(PRE, wblk*64 + 63);     // rows p >= pmax: no j>p in this block
  int pm = min(p1, pmax);
  if (p0 >= pmax){                       // whole chunk above diagonal -> zero-fill only
    for (int w = p0*2 + lane; w < p1*2; w += 64) mg[w] = 0u;
    return;
  }
  __shared__ float sx1[125], sy1[125], sx2[125], sy2[125], sar[125];
  int cnt = pm - p0;
  for (int i = lane; i < cnt; i += 64){
    float4 bb = lobox[(size_t)grp*PRE + p0 + i];
    sx1[i]=bb.x; sy1[i]=bb.y; sx2[i]=bb.z; sy2[i]=bb.w;
    sar[i]=loarea[(size_t)grp*PRE + p0 + i];
  }
  int j = wblk*64 + lane;
  float jx1=0.f,jy1=0.f,jx2=0.f,jy2=0.f,ja=0.f;
  if (j < PRE){
    float4 bb = lobox[(size_t)grp*PRE + j];
    jx1=bb.x; jy1=bb.y; jx2=bb.z; jy2=bb.w; ja=loarea[(size_t)grp*PRE + j];
  }
  __syncthreads();

#define IOU_HIT(PL, OUT) { \
    float bx1=sx1[PL], by1=sy1[PL], bx2=sx2[PL], by2=sy2[PL], ba=sar[PL]; \
    float ltx = fmaxf(bx1, jx1), lty = fmaxf(by1, jy1); \
    float rbx = fminf(bx2, jx2), rby = fminf(by2, jy2); \
    float ww = fmaxf(__fsub_rn(rbx,ltx), 0.0f); \
    float hh = fmaxf(__fsub_rn(rby,lty), 0.0f); \
    float inter = __fmul_rn(ww,hh); \
    float uni = __fsub_rn(__fadd_rn(ba, ja), inter); \
    OUT = (__fdiv_rn(inter,uni) > 0.7f) && (j > (p0 + (PL))) && (j < PRE); }

  int c = 0;
  for (; c + 4 <= cnt; c += 4){
    bool h0,h1,h2,h3;
    IOU_HIT(c,   h0);
    IOU_HIT(c+1, h1);
    IOU_HIT(c+2, h2);
    IOU_HIT(c+3, h3);
    unsigned long long b0 = __ballot(h0), b1 = __ballot(h1);
    unsigned long long b2 = __ballot(h2), b3 = __ballot(h3);
    if ((lane & 31) == 0){
      int d = lane >> 5;
      mg[(p0+c  )*2 + d] = (lane==0) ? (unsigned)b0 : (unsigned)(b0>>32);
      mg[(p0+c+1)*2 + d] = (lane==0) ? (unsigned)b1 : (unsigned)(b1>>32);
      mg[(p0+c+2)*2 + d] = (lane==0) ? (unsigned)b2 : (unsigned)(b2>>32);
      mg[(p0+c+3)*2 + d] = (lane==0) ? (unsigned)b3 : (unsigned)(b3>>32);
    }
  }
  for (; c < cnt; ++c){
    bool h; IOU_HIT(c, h);
    unsigned long long bal = __ballot(h);
    if ((lane & 31) == 0)
      mg[(p0+c)*2 + (lane>>5)] = (lane==0) ? (unsigned)bal : (unsigned)(bal>>32);
  }
#undef IOU_HIT
  for (int w = pm*2 + lane; w < p1*2; w += 64) mg[w] = 0u;   // rows [pm, p1) zero
}

// ---------------- K6b: tile-parallel greedy scan, latency-batched TPROC ----------------
__global__ __launch_bounds__(64) void k_scan_nms5(const unsigned* rankinfo, const unsigned* lmat,
                                                  const float4* lbox, const float* lskey, float* out){
  __shared__ unsigned lrows[64][36];     // row-major tile; stride 36 words
  __shared__ unsigned lsup[160];         // 5 levels x 32 words suppression state
  int n = blockIdx.x; int lane = threadIdx.x;
  int n5 = n*5;
  const unsigned* rin = rankinfo + (size_t)n*K_SEL;
  float* outn = out + (size_t)n*PRE*5;
  for (int i = lane; i < PRE*5; i += 64) outn[i] = 0.0f;   // own-image zero (replaces memset)
  for (int i = lane; i < 160; i += 64) lsup[i] = 0u;
  int kept_total = 0;
  uint2 Pa,Pb,Pc,Pd,Pe,Pf,Pg,Ph,Pi,Pj,Pk,Pl,Pm,Pn,Po,Pp;  // 16x8B staging
  float4 boxP; float scP = 0.f;
  unsigned infoC, infoN;
  int rgrp = lane >> 4;                  // 0..3: row subgroup
  unsigned wboff = (unsigned)(lane & 15) * (2u*PRE);  // my wblk's column segment
  int wb2 = (lane & 15) << 1;            // word index within row

#define SLOAD(INFO) { \
    unsigned L_ = ((INFO)>>10)&7u; unsigned p_ = (INFO) & 1023u; \
    unsigned rowu_ = ((unsigned)n5 + L_)*GRPW + p_*2u; \
    unsigned rb_; \
    rb_ = __shfl(rowu_,  0 + rgrp); Pa = *(const uint2*)(lmat + rb_ + wboff); \
    rb_ = __shfl(rowu_,  4 + rgrp); Pb = *(const uint2*)(lmat + rb_ + wboff); \
    rb_ = __shfl(rowu_,  8 + rgrp); Pc = *(const uint2*)(lmat + rb_ + wboff); \
    rb_ = __shfl(rowu_, 12 + rgrp); Pd = *(const uint2*)(lmat + rb_ + wboff); \
    rb_ = __shfl(rowu_, 16 + rgrp); Pe = *(const uint2*)(lmat + rb_ + wboff); \
    rb_ = __shfl(rowu_, 20 + rgrp); Pf = *(const uint2*)(lmat + rb_ + wboff); \
    rb_ = __shfl(rowu_, 24 + rgrp); Pg = *(const uint2*)(lmat + rb_ + wboff); \
    rb_ = __shfl(rowu_, 28 + rgrp); Ph = *(const uint2*)(lmat + rb_ + wboff); \
    rb_ = __shfl(rowu_, 32 + rgrp); Pi = *(const uint2*)(lmat + rb_ + wboff); \
    rb_ = __shfl(rowu_, 36 + rgrp); Pj = *(const uint2*)(lmat + rb_ + wboff); \
    rb_ = __shfl(rowu_, 40 + rgrp); Pk = *(const uint2*)(lmat + rb_ + wboff); \
    rb_ = __shfl(rowu_, 44 + rgrp); Pl = *(const uint2*)(lmat + rb_ + wboff); \
    rb_ = __shfl(rowu_, 48 + rgrp); Pm = *(const uint2*)(lmat + rb_ + wboff); \
    rb_ = __shfl(rowu_, 52 + rgrp); Pn = *(const uint2*)(lmat + rb_ + wboff); \
    rb_ = __shfl(rowu_, 56 + rgrp); Po = *(const uint2*)(lmat + rb_ + wboff); \
    rb_ = __shfl(rowu_, 60 + rgrp); Pp = *(const uint2*)(lmat + rb_ + wboff); \
    size_t bi_ = (size_t)((unsigned)n5 + L_)*PRE + p_; \
    boxP = lbox[bi_]; scP = lskey[bi_]; }

#define SWRITE() { \
    *(uint2*)&lrows[ 0 + rgrp][wb2] = Pa; *(uint2*)&lrows[ 4 + rgrp][wb2] = Pb; \
    *(uint2*)&lrows[ 8 + rgrp][wb2] = Pc; *(uint2*)&lrows[12 + rgrp][wb2] = Pd; \
    *(uint2*)&lrows[16 + rgrp][wb2] = Pe; *(uint2*)&lrows[20 + rgrp][wb2] = Pf; \
    *(uint2*)&lrows[24 + rgrp][wb2] = Pg; *(uint2*)&lrows[28 + rgrp][wb2] = Ph; \
    *(uint2*)&lrows[32 + rgrp][wb2] = Pi; *(uint2*)&lrows[36 + rgrp][wb2] = Pj; \
    *(uint2*)&lrows[40 + rgrp][wb2] = Pk; *(uint2*)&lrows[44 + rgrp][wb2] = Pl; \
    *(uint2*)&lrows[48 + rgrp][wb2] = Pm; *(uint2*)&lrows[52 + rgrp][wb2] = Pn; \
    *(uint2*)&lrows[56 + rgrp][wb2] = Po; *(uint2*)&lrows[60 + rgrp][wb2] = Pp; }

#define GRP16(B, ACC, SH) { \
    unsigned q0_=lrows[(B)+ 0][idxw_], q1_=lrows[(B)+ 1][idxw_], \
             q2_=lrows[(B)+ 2][idxw_], q3_=lrows[(B)+ 3][idxw_], \
             q4_=lrows[(B)+ 4][idxw_], q5_=lrows[(B)+ 5][idxw_], \
             q6_=lrows[(B)+ 6][idxw_], q7_=lrows[(B)+ 7][idxw_], \
             q8_=lrows[(B)+ 8][idxw_], q9_=lrows[(B)+ 9][idxw_], \
             qa_=lrows[(B)+10][idxw_], qb_=lrows[(B)+11][idxw_], \
             qc_=lrows[(B)+12][idxw_], qd_=lrows[(B)+13][idxw_], \
             qe_=lrows[(B)+14][idxw_], qf_=lrows[(B)+15][idxw_]; \
    ACC |= (((q0_>>pb_)&1u)<<((SH)+ 0)) | (((q1_>>pb_)&1u)<<((SH)+ 1)) \
         | (((q2_>>pb_)&1u)<<((SH)+ 2)) | (((q3_>>pb_)&1u)<<((SH)+ 3)) \
         | (((q4_>>pb_)&1u)<<((SH)+ 4)) | (((q5_>>pb_)&1u)<<((SH)+ 5)) \
         | (((q6_>>pb_)&1u)<<((SH)+ 6)) | (((q7_>>pb_)&1u)<<((SH)+ 7)) \
         | (((q8_>>pb_)&1u)<<((SH)+ 8)) | (((q9_>>pb_)&1u)<<((SH)+ 9)) \
         | (((qa_>>pb_)&1u)<<((SH)+10)) | (((qb_>>pb_)&1u)<<((SH)+11)) \
         | (((qc_>>pb_)&1u)<<((SH)+12)) | (((qd_>>pb_)&1u)<<((SH)+13)) \
         | (((qe_>>pb_)&1u)<<((SH)+14)) | (((qf_>>pb_)&1u)<<((SH)+15)); }

#define TPROC(INFO, BOX, SC, baseexpr) { \
    int base_ = (baseexpr); \
    unsigned L_ = ((INFO)>>10)&7u; unsigned p_ = (INFO) & 1023u; \
    int idxw_ = (int)(p_ >> 5); unsigned pb_ = p_ & 31u; \
    unsigned long long lb0_=__ballot(L_==0u), lb1_=__ballot(L_==1u), \
                       lb2_=__ballot(L_==2u), lb3_=__ballot(L_==3u), lb4_=__ballot(L_==4u); \
    unsigned long long myLvl_ = (L_==0u)?lb0_:(L_==1u)?lb1_:(L_==2u)?lb2_:(L_==3u)?lb3_:lb4_; \
    unsigned sw_ = lsup[L_*32u + (unsigned)idxw_]; \
    bool ok_ = ((((INFO)>>13)&1u)!=0u) && (base_ + lane < K_SEL) && (((sw_>>pb_)&1u)==0u); \
    unsigned long long cand_ = __ballot(ok_); \
    unsigned alo_ = 0u, ahi_ = 0u; \
    GRP16( 0, alo_,  0); GRP16(16, alo_, 16); \
    GRP16(32, ahi_,  0); GRP16(48, ahi_, 16); \
    unsigned long long cm_ = ((((unsigned long long)ahi_)<<32)|(unsigned long long)alo_) & myLvl_; \
    unsigned long long keptM_ = 0ull; \
    while (cand_){ \
      bool safe_ = (((cand_>>lane)&1ull)!=0ull) && ((cm_ & cand_)==0ull); \
      unsigned long long nk_ = __ballot(safe_); \
      keptM_ |= nk_; \
      bool dead_ = (((cand_>>lane)&1ull)!=0ull) && ((cm_ & nk_)!=0ull); \
      cand_ &= ~(nk_ | __ballot(dead_)); \
    } \
    if (((keptM_>>lane)&1ull)!=0ull){ \
      unsigned sb_ = L_*32u; \
      _Pragma("unroll") \
      for (int k_ = 0; k_ < 32; ++k_){ \
        unsigned w_ = (unsigned)((k_+lane)&31); \
        atomicOr(&lsup[sb_+w_], lrows[lane][w_]); \
      } \
    } \
    int pos_ = kept_total + (int)__popcll(keptM_ & ((1ull<<lane)-1ull)); \
    if ((((keptM_>>lane)&1ull)!=0ull) && pos_ < PRE){ \
      float* orow_ = outn + (size_t)pos_*5; \
      orow_[0]=(BOX).x; orow_[1]=(BOX).y; orow_[2]=(BOX).z; orow_[3]=(BOX).w; orow_[4]=(SC); \
    } \
    kept_total += (int)__popcll(keptM_); \
    asm volatile("s_waitcnt lgkmcnt(0)" ::: "memory"); \
  }

  infoC = rin[lane];
  SLOAD(infoC);                          // tile 0 rows -> regs, box -> boxP
  SWRITE();                              // tile 0 rows -> LDS
  float4 boxC = boxP; float scC = scP;
  infoN = rin[64 + lane];

  for (int t = 0; t < TILES; ++t){
    if (t+1 < TILES) SLOAD(infoN);       // issue next tile's loads (rows + box)
    asm volatile("s_waitcnt lgkmcnt(0)" ::: "memory");   // lrows writes visible
    TPROC(infoC, boxC, scC, t*64);
    if (kept_total >= PRE) break;
    if (t+1 < TILES){
      SWRITE();                          // waits next tile's loads (covered by TPROC)
      boxC = boxP; scC = scP;
      infoC = infoN;
      if (t+2 < TILES){
        int nx = (t+2)*64 + lane; if (nx > K_SEL-1) nx = K_SEL-1;
        infoN = rin[nx];
      }
    }
  }
#undef SLOAD
#undef SWRITE
#undef GRP16
#undef TPROC
}

// ---------------- fallback path (ws too small): round-3 kernels ----------------
__global__ __launch_bounds__(256) void k_sortimg(const unsigned long long* keys,
                                                 const float* d0,const float* d1,const float* d2,const float* d3,const float* d4,
                                                 const float* anchors,
                                                 float4* sbox, float* sskey, int* slvl){
  int n = blockIdx.x;
  __shared__ unsigned long long sk[8192];
  for (int i = threadIdx.x; i < 8192; i += 256)
    sk[i] = (i < K_SEL) ? keys[(size_t)n*K_SEL + i] : ~0ULL;
  __syncthreads();
  bitonic<8192>(sk);
  for (int r = threadIdx.x; r < K_SEL; r += 256){
    unsigned long long key = sk[r];
    int t = (int)(key & 0x7FFFFu);
    int lvl = (int)((key >> 19) & 7u);
    unsigned se = ~((unsigned)(key >> 22));
    const float* dl = sel5(lvl,d0,d1,d2,d3,d4);
    BoxV b = decode_box(lvl, t, n, dl, anchors);
    sbox[(size_t)n*K_SEL + r] = make_float4(b.x1,b.y1,b.x2,b.y2);
    sskey[(size_t)n*K_SEL + r] = s2f(se);
    slvl[(size_t)n*K_SEL + r] = lvl;
  }
}

__global__ __launch_bounds__(256) void k_nms(const float4* sbox, const float* sskey, const int* slvl, float* out){
  int n = blockIdx.x, tid = threadIdx.x;
  __shared__ float kx1[PRE], ky1[PRE], kx2[PRE], ky2[PRE], kar[PRE];
  __shared__ int klv[PRE];
  __shared__ int nv_s, flag_s;
  for (int i = tid; i < PRE*5; i += 256) out[(size_t)n*PRE*5 + i] = 0.0f;
  if (tid == 0){ nv_s = 0; flag_s = 0; }
  __syncthreads();
  int c = 0;
  for (int i = tid; i < K_SEL; i += 256)
    if (sskey[(size_t)n*K_SEL + i] != -INFINITY) ++c;
  atomicAdd(&nv_s, c);
  __syncthreads();
  int nvalid = nv_s;
  int kept = 0;
  for (int i = 0; i < nvalid; ++i){
    float4 b = sbox[(size_t)n*K_SEL + i];
    int lv = slvl[(size_t)n*K_SEL + i];
    float off = (float)lv * 1345.0f;
    float ox1 = __fadd_rn(b.x, off), oy1 = __fadd_rn(b.y, off);
    float ox2 = __fadd_rn(b.z, off), oy2 = __fadd_rn(b.w, off);
    float area = __fmul_rn(__fsub_rn(ox2,ox1), __fsub_rn(oy2,oy1));
    bool hit = false;
    for (int j = tid; j < kept; j += 256){
      if (klv[j] == lv){
        float ltx = fmaxf(kx1[j], ox1), lty = fmaxf(ky1[j], oy1);
        float rbx = fminf(kx2[j], ox2), rby = fminf(ky2[j], oy2);
        float w = fmaxf(__fsub_rn(rbx,ltx), 0.0f);
        float h = fmaxf(__fsub_rn(rby,lty), 0.0f);
        float inter = __fmul_rn(w,h);
        float uni = __fsub_rn(__fadd_rn(kar[j], area), inter);
        if (__fdiv_rn(inter,uni) > 0.7f) hit = true;
      }
    }
    if (hit) flag_s = 1;
    __syncthreads();
    int sup = flag_s;
    __syncthreads();
    if (!sup){
      if (tid == 0){
        kx1[kept]=ox1; ky1[kept]=oy1; kx2[kept]=ox2; ky2[kept]=oy2; kar[kept]=area; klv[kept]=lv;
        float* orow = out + (size_t)n*PRE*5 + (size_t)kept*5;
        orow[0]=b.x; orow[1]=b.y; orow[2]=b.z; orow[3]=b.w;
        orow[4]=sskey[(size_t)n*K_SEL + i];
      }
      ++kept;
    }
    if (tid == 0) flag_s = 0;
    __syncthreads();
    if (kept == PRE) break;
  }
}

extern "C" void kernel_launch(void* const* d_in, const int* in_sizes, int n_in,
                              void* d_out, int out_size, void* d_ws, size_t ws_size,
                              hipStream_t stream) {
  bool interleaved = (in_sizes[1] == 4*in_sizes[0]);
  const float* obj[5]; const float* dlt[5];
  for (int i = 0; i < 5; ++i){
    if (interleaved){ obj[i] = (const float*)d_in[2*i]; dlt[i] = (const float*)d_in[2*i+1]; }
    else            { obj[i] = (const float*)d_in[i];   dlt[i] = (const float*)d_in[5+i]; }
  }
  const float* anchors = (const float*)d_in[10];

  char* ws = (char*)d_ws;
  unsigned* hist            = (unsigned*)(ws);                     // 655360
  unsigned* cnt_gt          = (unsigned*)(ws + 655360);            // 160
  unsigned* cnt_eq          = (unsigned*)(ws + 655520);            // 160
  unsigned* thi             = (unsigned*)(ws + 655680);            // 160 -> counters end 655840
  unsigned long long* cand  = (unsigned long long*)(ws + 655840);  // 1310720 -> 1966560
  unsigned long long* keys  = (unsigned long long*)(ws + 1966560); // 320000 -> 2286560
  float4* lbox              = (float4*)(ws + 2286560);             // 640000 -> 2926560
  float4* lobox             = (float4*)(ws + 2926560);             // 640000 -> 3566560
  float* loarea             = (float*)(ws + 3566560);              // 160000 -> 3726560
  float* lskey              = (float*)(ws + 3726560);              // 160000 -> 3886560
  unsigned* rankinfo        = (unsigned*)(ws + 3886560);           // 160000 -> 4046560
  unsigned* lmat            = (unsigned*)(ws + 4046560);           // 5120000 -> 9166560
  float4* sbox              = (float4*)(ws + 9166560);             // fallback: 640000 -> 9806560
  float* sskey              = (float*)(ws + 9806560);              // 160000 -> 9966560
  int* slvl                 = (int*)(ws + 9966560);                // 160000 -> 10126560
  const size_t NEED = 10126560;

  hipMemsetAsync(ws, 0, 655840, stream);   // hist + counters

  dim3 gChunk(42, 40);                   // 42 chunks x 8192 covers level-0's 338688
  k_hist<<<gChunk, 256, 0, stream>>>(obj[0],obj[1],obj[2],obj[3],obj[4], hist);
  k_scan<<<40, 256, 0, stream>>>(hist, thi);
  k_compact<<<gChunk, 256, 0, stream>>>(obj[0],obj[1],obj[2],obj[3],obj[4],
                                        dlt[0],dlt[1],dlt[2],dlt[3],dlt[4],
                                        anchors, thi, cnt_gt, cnt_eq, cand, keys);
  k_tiesel<<<dim3(16, 40), 256, 0, stream>>>(dlt[0],dlt[1],dlt[2],dlt[3],dlt[4], anchors,
                                             cnt_gt, cnt_eq, cand, keys);
  if (ws_size >= NEED){
    k_sortlvl<<<40, 256, 0, stream>>>(keys);
    k_declvl<<<dim3(8, 40), 256, 0, stream>>>(keys, dlt[0],dlt[1],dlt[2],dlt[3],dlt[4], anchors,
                                              lbox, lobox, loarea, lskey);
    k_rank<<<200, 256, 0, stream>>>(keys, rankinfo);
    k_ioumat_lvl<<<dim3(128, 40), 64, 0, stream>>>(lobox, loarea, lmat);
    k_scan_nms5<<<8, 64, 0, stream>>>(rankinfo, lmat, lbox, lskey, (float*)d_out);
  } else {
    k_sortimg<<<8, 256, 0, stream>>>(keys, dlt[0],dlt[1],dlt[2],dlt[3],dlt[4], anchors,
                                     sbox, sskey, slvl);
    k_nms<<<8, 256, 0, stream>>>(sbox, sskey, slvl, (float*)d_out);
  }
}

// Round 18
// 196.284 us; speedup vs baseline: 1.4636x; 1.0588x over previous
//
#include <hip/hip_runtime.h>
#include <cmath>

#define N_IMG   8
#define PRE     1000
#define K_SEL   5000
#define NBIN    4096
#define TIE_CAP 4096
#define IMG_F   1344.0f
#define S_NEGINF 0x007FFFFFu
#define TILES   79             // ceil(5000/64)
#define GRPW    32000          // words per grp in lmat: 16 wblk x 1000 p x 2
#define CHUNK   8192           // elements per block in k_hist/k_compact

__constant__ int c_W[5]   = {336,168,84,42,21};
__constant__ int c_HW[5]  = {112896,28224,7056,1764,441};
__constant__ int c_OFF[5] = {0,338688,423360,444528,449820};

__device__ __forceinline__ unsigned f2s(float f){
  unsigned u = __float_as_uint(f);
  return (u & 0x80000000u) ? ~u : (u | 0x80000000u);
}
__device__ __forceinline__ float s2f(unsigned s){
  unsigned u = (s & 0x80000000u) ? (s & 0x7FFFFFFFu) : ~s;
  return __uint_as_float(u);
}
__device__ __forceinline__ const float* sel5(int l, const float* p0,const float* p1,const float* p2,const float* p3,const float* p4){
  switch(l){case 0:return p0;case 1:return p1;case 2:return p2;case 3:return p3;default:return p4;}
}

struct BoxV { float x1,y1,x2,y2; bool valid; };

// Bit-faithful torchvision BoxCoder.decode + clip + min-size validity.
__device__ BoxV decode_box(int lvl, int t, int n, const float* dl, const float* anchors){
  int HW = c_HW[lvl], W = c_W[lvl];
  int a = t % 3, pos = t / 3;          // t = (h*W+w)*3 + a
  int h = pos / W, w = pos - h*W;
  int g = c_OFF[lvl] + t;
  const float* an = anchors + (size_t)4*(size_t)g;
  float a0=an[0], a1=an[1], a2=an[2], a3=an[3];
  float aw = __fsub_rn(a2,a0), ah = __fsub_rn(a3,a1);
  float acx = __fadd_rn(a0, __fmul_rn(0.5f,aw));
  float acy = __fadd_rn(a1, __fmul_rn(0.5f,ah));
  const float* dp = dl + ((size_t)n*12 + (size_t)a*4)*(size_t)HW + (size_t)h*W + (size_t)w;
  float dx = dp[0], dy = dp[HW], dwv = dp[2*(size_t)HW], dhv = dp[3*(size_t)HW];
  const float CLAMP = (float)4.135166556742356;  // log(1000/16)
  dwv = fminf(dwv, CLAMP); dhv = fminf(dhv, CLAMP);
  float pcx = __fadd_rn(__fmul_rn(dx,aw), acx);
  float pcy = __fadd_rn(__fmul_rn(dy,ah), acy);
  float pw = __fmul_rn((float)::exp((double)dwv), aw);
  float ph = __fmul_rn((float)::exp((double)dhv), ah);
  float hx = __fmul_rn(0.5f,pw), hy = __fmul_rn(0.5f,ph);
  BoxV b;
  b.x1 = fminf(fmaxf(__fsub_rn(pcx,hx),0.0f),IMG_F);
  b.y1 = fminf(fmaxf(__fsub_rn(pcy,hy),0.0f),IMG_F);
  b.x2 = fminf(fmaxf(__fadd_rn(pcx,hx),0.0f),IMG_F);
  b.y2 = fminf(fmaxf(__fadd_rn(pcy,hy),0.0f),IMG_F);
  b.valid = (__fsub_rn(b.x2,b.x1) >= 1e-3f) && (__fsub_rn(b.y2,b.y1) >= 1e-3f);
  return b;
}

// key = (~s_eff)<<22 | lvl<<19 | t : ascending sort == (score desc, level asc, idx asc)
__device__ unsigned long long make_key(unsigned s, int lvl, int t, int n, const float* dl, const float* anchors){
  BoxV b = decode_box(lvl,t,n,dl,anchors);
  unsigned se = b.valid ? s : S_NEGINF;     // invalid -> skey = -inf
  return ((unsigned long long)(~se) << 22) | ((unsigned long long)(unsigned)lvl << 19) | (unsigned long long)(unsigned)t;
}

// ---------------- K1: per-(image,level) histogram (chunked grid, float4 loads) ----------------
__global__ __launch_bounds__(256) void k_hist(const float* o0,const float* o1,const float* o2,const float* o3,const float* o4,
                                              unsigned* hist){
  int grp = blockIdx.y; int n = grp/5, lvl = grp - n*5;
  int HW = c_HW[lvl], M = 3*HW;
  int base = blockIdx.x * CHUNK;
  if (base >= M) return;                 // idle block for short levels
  int end = min(base + CHUNK, M);
  const float* ob = sel5(lvl,o0,o1,o2,o3,o4) + (size_t)n*(size_t)M;
  __shared__ unsigned lh[NBIN];
  for (int b = threadIdx.x; b < NBIN; b += 256) lh[b] = 0;
  __syncthreads();
  bool vec4 = ((((size_t)ob) & 15) == 0) && ((M & 3) == 0);   // lvl 0-3 aligned; lvl4 scalar
  if (vec4){
    const float4* ob4 = (const float4*)ob;
    int b4 = base >> 2, e4 = end >> 2;
    for (int i = b4 + threadIdx.x; i < e4; i += 256){
      float4 v = ob4[i];
      atomicAdd(&lh[f2s(v.x) >> 20], 1u);
      atomicAdd(&lh[f2s(v.y) >> 20], 1u);
      atomicAdd(&lh[f2s(v.z) >> 20], 1u);
      atomicAdd(&lh[f2s(v.w) >> 20], 1u);
    }
  } else {
    for (int i = base + threadIdx.x; i < end; i += 256){
      unsigned s = f2s(ob[i]);
      atomicAdd(&lh[s >> 20], 1u);
    }
  }
  __syncthreads();
  unsigned* gh = hist + (size_t)grp*NBIN;
  for (int b = threadIdx.x; b < NBIN; b += 256){ unsigned v = lh[b]; if (v) atomicAdd(&gh[b], v); }
}

// ---------------- K2: find bin containing the 1000th-largest score ----------------
__global__ __launch_bounds__(256) void k_scan(const unsigned* hist, unsigned* thi){
  int grp = blockIdx.x;
  const unsigned* gh = hist + (size_t)grp*NBIN;
  __shared__ unsigned part[256];
  unsigned ssum = 0;
  int base = threadIdx.x*16;
  for (int b = base; b < base+16; ++b) ssum += gh[b];
  part[threadIdx.x] = ssum;
  __syncthreads();
  if (threadIdx.x == 0){
    int k = PRE;
    int c = 255;
    while ((int)part[c] < k){ k -= (int)part[c]; --c; }
    int b = c*16 + 15;
    while ((int)gh[b] < k){ k -= (int)gh[b]; --b; }
    thi[grp] = (unsigned)b;
  }
}

// ---------------- K3: compact >bin elements (two-phase; float4 classify) ----------------
__global__ __launch_bounds__(256) void k_compact(const float* o0,const float* o1,const float* o2,const float* o3,const float* o4,
                                                 const float* d0,const float* d1,const float* d2,const float* d3,const float* d4,
                                                 const float* anchors, const unsigned* thi,
                                                 unsigned* cnt_gt, unsigned* cnt_eq,
                                                 unsigned long long* cand, unsigned long long* keys){
  int grp = blockIdx.y; int n = grp/5, lvl = grp - n*5;
  int HW = c_HW[lvl], M = 3*HW;
  int base = blockIdx.x * CHUNK;
  if (base >= M) return;
  int end = min(base + CHUNK, M);
  const float* ob = sel5(lvl,o0,o1,o2,o3,o4) + (size_t)n*(size_t)M;
  const float* dl = sel5(lvl,d0,d1,d2,d3,d4);
  unsigned T = thi[grp];
  __shared__ int lgt[1024];              // per-group gt total < 1000 -> block gt <= 999
  __shared__ int leq[TIE_CAP];
  __shared__ unsigned cgt_s, ceq_s, bgt_s, beq_s;
  if (threadIdx.x == 0){ cgt_s = 0u; ceq_s = 0u; }
  __syncthreads();
  bool vec4 = ((((size_t)ob) & 15) == 0) && ((M & 3) == 0);
#define CLS(SH, I) { \
    if ((SH) > T){ unsigned k = atomicAdd(&cgt_s, 1u); if (k < 1024u) lgt[k] = (I); } \
    else if ((SH) == T){ unsigned k = atomicAdd(&ceq_s, 1u); if (k < (unsigned)TIE_CAP) leq[k] = (I); } }
  if (vec4){
    const float4* ob4 = (const float4*)ob;
    int b4 = base >> 2, e4 = end >> 2;
    for (int i = b4 + threadIdx.x; i < e4; i += 256){
      float4 v = ob4[i];
      unsigned s0 = f2s(v.x) >> 20, s1 = f2s(v.y) >> 20;
      unsigned s2 = f2s(v.z) >> 20, s3 = f2s(v.w) >> 20;
      int i4 = i << 2;
      CLS(s0, i4); CLS(s1, i4+1); CLS(s2, i4+2); CLS(s3, i4+3);
    }
  } else {
    for (int i = base + threadIdx.x; i < end; i += 256){
      unsigned sh = f2s(ob[i]) >> 20;
      CLS(sh, i);
    }
  }
#undef CLS
  __syncthreads();
  if (threadIdx.x == 0){
    bgt_s = atomicAdd(&cnt_gt[grp], min(cgt_s, 1024u));
    beq_s = atomicAdd(&cnt_eq[grp], min(ceq_s, (unsigned)TIE_CAP));
  }
  __syncthreads();
  unsigned cg = min(cgt_s, 1024u), ce = min(ceq_s, (unsigned)TIE_CAP);
  unsigned bgt = bgt_s, beq = beq_s;
  unsigned long long* kout = keys + (size_t)n*K_SEL + (size_t)lvl*PRE;
  for (unsigned k = threadIdx.x; k < cg; k += 256){
    int i = lgt[k];
    unsigned s = f2s(ob[i]);
    int a = i / HW; int rem = i - a*HW; int t = rem*3 + a;
    kout[bgt + k] = make_key(s, lvl, t, n, dl, anchors);
  }
  for (unsigned k = threadIdx.x; k < ce; k += 256){
    unsigned e = beq + k;
    if (e < (unsigned)TIE_CAP){
      int i = leq[k];
      unsigned s = f2s(ob[i]);
      int a = i / HW; int rem = i - a*HW; int t = rem*3 + a;
      cand[(size_t)grp*TIE_CAP + e] = ((unsigned long long)(~s) << 19) | (unsigned long long)(unsigned)t;
    }
  }
}

template<int SZ>
__device__ void bitonic(unsigned long long* sk){
  for (int k = 2; k <= SZ; k <<= 1){
    for (int j = k >> 1; j > 0; j >>= 1){
      for (int i = threadIdx.x; i < SZ; i += blockDim.x){
        int ix = i ^ j;
        if (ix > i){
          unsigned long long va = sk[i], vb = sk[ix];
          if ((va > vb) == ((i & k) == 0)){ sk[i] = vb; sk[ix] = va; }
        }
      }
      __syncthreads();
    }
  }
}

// ---------------- K4: boundary selection via rank-select, 16 runtime chunks/group ----------------
__global__ __launch_bounds__(256) void k_tiesel(const float* d0,const float* d1,const float* d2,const float* d3,const float* d4,
                                                const float* anchors,
                                                const unsigned* cnt_gt, const unsigned* cnt_eq,
                                                const unsigned long long* cand, unsigned long long* keys){
  int grp = blockIdx.y; int n = grp/5, lvl = grp - n*5;
  int q = blockIdx.x;                    // 16 runtime chunks
  __shared__ unsigned long long sk[TIE_CAP];
  int ne = min((int)cnt_eq[grp], TIE_CAP);
  int cg = (int)cnt_gt[grp];
  int need = PRE - cg;
  const float* dl = sel5(lvl,d0,d1,d2,d3,d4);
  unsigned long long* kout = keys + (size_t)n*K_SEL + (size_t)lvl*PRE + cg;
  if (q == 0){  // pathological overflow pad (ne < need): harmless invalid keys
    for (int j = ne + threadIdx.x; j < need; j += 256)
      kout[j] = ((unsigned long long)(~S_NEGINF) << 22);
  }
  int chunk = (ne + 15) >> 4;
  int c0 = q*chunk, c1 = min(ne, c0 + chunk);
  if (c0 >= ne) return;
  for (int i = threadIdx.x; i < ne; i += 256)
    sk[i] = cand[(size_t)grp*TIE_CAP + i];
  __syncthreads();
  for (int c = c0 + threadIdx.x; c < c1; c += 256){
    unsigned long long ck = sk[c];
    int rank = 0;
    int i = 0;
    for (; i + 8 <= ne; i += 8){
      rank += (int)(sk[i  ] < ck) + (int)(sk[i+1] < ck)
            + (int)(sk[i+2] < ck) + (int)(sk[i+3] < ck)
            + (int)(sk[i+4] < ck) + (int)(sk[i+5] < ck)
            + (int)(sk[i+6] < ck) + (int)(sk[i+7] < ck);
    }
    for (; i < ne; ++i) rank += (int)(sk[i] < ck);
    if (rank < need){
      unsigned t = (unsigned)(ck & 0x7FFFFu);
      unsigned s = ~((unsigned)(ck >> 19));
      kout[rank] = make_key(s, lvl, (int)t, n, dl, anchors);
    }
  }
}

// ---------------- K5a: sort each (image,level) run (sort only; decode split out) ----------------
__global__ __launch_bounds__(256) void k_sortlvl(unsigned long long* keys){
  int grp = blockIdx.x; int n = grp/5, lvl = grp - n*5;
  __shared__ unsigned long long sk[1024];
  unsigned long long* kp = keys + (size_t)n*K_SEL + (size_t)lvl*PRE;
  for (int i = threadIdx.x; i < 1024; i += 256)
    sk[i] = (i < PRE) ? kp[i] : ~0ULL;
  __syncthreads();
  bitonic<1024>(sk);
  for (int i = threadIdx.x; i < PRE; i += 256) kp[i] = sk[i];
}

// ---------------- K5a2: decode sorted keys -> level-space arrays, 8 blocks/group ----------------
__global__ __launch_bounds__(256) void k_declvl(const unsigned long long* keys,
                                                const float* d0,const float* d1,const float* d2,const float* d3,const float* d4,
                                                const float* anchors,
                                                float4* lbox, float4* lobox, float* loarea, float* lskey){
  int grp = blockIdx.y; int n = grp/5, lvl = grp - n*5;
  if (threadIdx.x >= 125) return;
  int i = blockIdx.x*125 + threadIdx.x;  // 8 x 125 = 1000
  unsigned long long key = keys[(size_t)n*K_SEL + (size_t)lvl*PRE + i];
  int t = (int)(key & 0x7FFFFu);
  unsigned se = ~((unsigned)(key >> 22));
  const float* dl = sel5(lvl,d0,d1,d2,d3,d4);
  BoxV b = decode_box(lvl, t, n, dl, anchors);
  size_t o = (size_t)grp*PRE + i;
  lbox[o] = make_float4(b.x1,b.y1,b.x2,b.y2);
  lskey[o] = s2f(se);                   // -inf if invalid
  float off = (float)lvl * 1345.0f;     // (IMG+1) batched-NMS offset
  float ox1 = __fadd_rn(b.x1, off), oy1 = __fadd_rn(b.y1, off);
  float ox2 = __fadd_rn(b.x2, off), oy2 = __fadd_rn(b.y2, off);
  lobox[o] = make_float4(ox1,oy1,ox2,oy2);
  loarea[o] = __fmul_rn(__fsub_rn(ox2,ox1), __fsub_rn(oy2,oy1));
}

// ---------------- K5b: global rank, one block per (image, level) ----------------
// rankinfo[rank] = p | (lvl<<10) | (valid<<13)
__global__ __launch_bounds__(256) void k_rank(const unsigned long long* keys, unsigned* rankinfo){
  int grp5 = blockIdx.x;                 // n*5 + lvl
  int n = grp5/5, lvl = grp5 - n*5;
  __shared__ unsigned long long sl[K_SEL];
  for (int i = threadIdx.x; i < K_SEL; i += 256) sl[i] = keys[(size_t)n*K_SEL + i];
  __syncthreads();
  for (int j = threadIdx.x; j < PRE; j += 256){
    unsigned long long k = sl[lvl*PRE + j];
    int rank = j;
    #pragma unroll
    for (int m = 0; m < 5; ++m){
      if (m == lvl) continue;
      const unsigned long long* s = sl + m*PRE;
      int lo = 0, hi = PRE;
      while (lo < hi){ int mid = (lo+hi) >> 1; if (s[mid] < k) lo = mid+1; else hi = mid; }
      rank += lo;
    }
    unsigned se = ~((unsigned)(k >> 22));
    unsigned info = (unsigned)j | ((unsigned)lvl << 10) | ((se != S_NEGINF) ? (1u<<13) : 0u);
    rankinfo[(size_t)n*K_SEL + rank] = info;   // exact permutation of [0,5000)
  }
}

// ---------------- K6a: suppression bit-matrix, 1 wave per (wblk, 125-row p-chunk) ----------------
__global__ __launch_bounds__(64) void k_ioumat_lvl(const float4* lobox, const float* loarea, unsigned* lmat){
  int grp = blockIdx.y;                  // n*5 + L
  int bx = blockIdx.x;
  int wblk = bx >> 3;                    // 0..15: j-block (j = wblk*64 + lane)
  int pc   = bx & 7;                     // 0..7: p-chunk of 125
  int lane = threadIdx.x;
  int p0 = pc*125, p1 = p0 + 125;
  unsigned* mg = lmat + (size_t)grp*GRPW + (size_t)wblk*2*PRE;
  int pmax = min(PRE, wblk*64 + 63);     // rows p >= pmax: no j>p in this block
  int pm = min(p1, pmax);
  if (p0 >= pmax){                       // whole chunk above diagonal -> zero-fill only
    for (int w = p0*2 + lane; w < p1*2; w += 64) mg[w] = 0u;
    return;
  }
  __shared__ float sx1[125], sy1[125], sx2[125], sy2[125], sar[125];
  int cnt = pm - p0;
  for (int i = lane; i < cnt; i += 64){
    float4 bb = lobox[(size_t)grp*PRE + p0 + i];
    sx1[i]=bb.x; sy1[i]=bb.y; sx2[i]=bb.z; sy2[i]=bb.w;
    sar[i]=loarea[(size_t)grp*PRE + p0 + i];
  }
  int j = wblk*64 + lane;
  float jx1=0.f,jy1=0.f,jx2=0.f,jy2=0.f,ja=0.f;
  if (j < PRE){
    float4 bb = lobox[(size_t)grp*PRE + j];
    jx1=bb.x; jy1=bb.y; jx2=bb.z; jy2=bb.w; ja=loarea[(size_t)grp*PRE + j];
  }
  __syncthreads();

#define IOU_HIT(PL, OUT) { \
    float bx1=sx1[PL], by1=sy1[PL], bx2=sx2[PL], by2=sy2[PL], ba=sar[PL]; \
    float ltx = fmaxf(bx1, jx1), lty = fmaxf(by1, jy1); \
    float rbx = fminf(bx2, jx2), rby = fminf(by2, jy2); \
    float ww = fmaxf(__fsub_rn(rbx,ltx), 0.0f); \
    float hh = fmaxf(__fsub_rn(rby,lty), 0.0f); \
    float inter = __fmul_rn(ww,hh); \
    float uni = __fsub_rn(__fadd_rn(ba, ja), inter); \
    OUT = (__fdiv_rn(inter,uni) > 0.7f) && (j > (p0 + (PL))) && (j < PRE); }

  int c = 0;
  for (; c + 4 <= cnt; c += 4){
    bool h0,h1,h2,h3;
    IOU_HIT(c,   h0);
    IOU_HIT(c+1, h1);
    IOU_HIT(c+2, h2);
    IOU_HIT(c+3, h3);
    unsigned long long b0 = __ballot(h0), b1 = __ballot(h1);
    unsigned long long b2 = __ballot(h2), b3 = __ballot(h3);
    if ((lane & 31) == 0){
      int d = lane >> 5;
      mg[(p0+c  )*2 + d] = (lane==0) ? (unsigned)b0 : (unsigned)(b0>>32);
      mg[(p0+c+1)*2 + d] = (lane==0) ? (unsigned)b1 : (unsigned)(b1>>32);
      mg[(p0+c+2)*2 + d] = (lane==0) ? (unsigned)b2 : (unsigned)(b2>>32);
      mg[(p0+c+3)*2 + d] = (lane==0) ? (unsigned)b3 : (unsigned)(b3>>32);
    }
  }
  for (; c < cnt; ++c){
    bool h; IOU_HIT(c, h);
    unsigned long long bal = __ballot(h);
    if ((lane & 31) == 0)
      mg[(p0+c)*2 + (lane>>5)] = (lane==0) ? (unsigned)bal : (unsigned)(bal>>32);
  }
#undef IOU_HIT
  for (int w = pm*2 + lane; w < p1*2; w += 64) mg[w] = 0u;   // rows [pm, p1) zero
}

// ---------------- K6b: tile-parallel greedy scan; sparse 64-bit sup update ----------------
__global__ __launch_bounds__(64) void k_scan_nms5(const unsigned* rankinfo, const unsigned* lmat,
                                                  const float4* lbox, const float* lskey, float* out){
  __shared__ unsigned lrows[64][36];     // row-major tile; stride 36 words (rows 16B-aligned)
  __shared__ unsigned long long lsup2[80];  // 5 levels x 16 dword-pairs suppression state
  int n = blockIdx.x; int lane = threadIdx.x;
  int n5 = n*5;
  const unsigned* rin = rankinfo + (size_t)n*K_SEL;
  float* outn = out + (size_t)n*PRE*5;
  for (int i = lane; i < PRE*5; i += 64) outn[i] = 0.0f;   // own-image zero
  for (int i = lane; i < 80; i += 64) lsup2[i] = 0ull;
  int kept_total = 0;
  uint2 Pa,Pb,Pc,Pd,Pe,Pf,Pg,Ph,Pi,Pj,Pk,Pl,Pm,Pn,Po,Pp;  // 16x8B staging
  float4 boxP; float scP = 0.f;
  unsigned infoC, infoN;
  int rgrp = lane >> 4;                  // 0..3: row subgroup
  unsigned wboff = (unsigned)(lane & 15) * (2u*PRE);  // my wblk's column segment
  int wb2 = (lane & 15) << 1;            // word index within row

#define SLOAD(INFO) { \
    unsigned L_ = ((INFO)>>10)&7u; unsigned p_ = (INFO) & 1023u; \
    unsigned rowu_ = ((unsigned)n5 + L_)*GRPW + p_*2u; \
    unsigned rb_; \
    rb_ = __shfl(rowu_,  0 + rgrp); Pa = *(const uint2*)(lmat + rb_ + wboff); \
    rb_ = __shfl(rowu_,  4 + rgrp); Pb = *(const uint2*)(lmat + rb_ + wboff); \
    rb_ = __shfl(rowu_,  8 + rgrp); Pc = *(const uint2*)(lmat + rb_ + wboff); \
    rb_ = __shfl(rowu_, 12 + rgrp); Pd = *(const uint2*)(lmat + rb_ + wboff); \
    rb_ = __shfl(rowu_, 16 + rgrp); Pe = *(const uint2*)(lmat + rb_ + wboff); \
    rb_ = __shfl(rowu_, 20 + rgrp); Pf = *(const uint2*)(lmat + rb_ + wboff); \
    rb_ = __shfl(rowu_, 24 + rgrp); Pg = *(const uint2*)(lmat + rb_ + wboff); \
    rb_ = __shfl(rowu_, 28 + rgrp); Ph = *(const uint2*)(lmat + rb_ + wboff); \
    rb_ = __shfl(rowu_, 32 + rgrp); Pi = *(const uint2*)(lmat + rb_ + wboff); \
    rb_ = __shfl(rowu_, 36 + rgrp); Pj = *(const uint2*)(lmat + rb_ + wboff); \
    rb_ = __shfl(rowu_, 40 + rgrp); Pk = *(const uint2*)(lmat + rb_ + wboff); \
    rb_ = __shfl(rowu_, 44 + rgrp); Pl = *(const uint2*)(lmat + rb_ + wboff); \
    rb_ = __shfl(rowu_, 48 + rgrp); Pm = *(const uint2*)(lmat + rb_ + wboff); \
    rb_ = __shfl(rowu_, 52 + rgrp); Pn = *(const uint2*)(lmat + rb_ + wboff); \
    rb_ = __shfl(rowu_, 56 + rgrp); Po = *(const uint2*)(lmat + rb_ + wboff); \
    rb_ = __shfl(rowu_, 60 + rgrp); Pp = *(const uint2*)(lmat + rb_ + wboff); \
    size_t bi_ = (size_t)((unsigned)n5 + L_)*PRE + p_; \
    boxP = lbox[bi_]; scP = lskey[bi_]; }

#define SWRITE() { \
    *(uint2*)&lrows[ 0 + rgrp][wb2] = Pa; *(uint2*)&lrows[ 4 + rgrp][wb2] = Pb; \
    *(uint2*)&lrows[ 8 + rgrp][wb2] = Pc; *(uint2*)&lrows[12 + rgrp][wb2] = Pd; \
    *(uint2*)&lrows[16 + rgrp][wb2] = Pe; *(uint2*)&lrows[20 + rgrp][wb2] = Pf; \
    *(uint2*)&lrows[24 + rgrp][wb2] = Pg; *(uint2*)&lrows[28 + rgrp][wb2] = Ph; \
    *(uint2*)&lrows[32 + rgrp][wb2] = Pi; *(uint2*)&lrows[36 + rgrp][wb2] = Pj; \
    *(uint2*)&lrows[40 + rgrp][wb2] = Pk; *(uint2*)&lrows[44 + rgrp][wb2] = Pl; \
    *(uint2*)&lrows[48 + rgrp][wb2] = Pm; *(uint2*)&lrows[52 + rgrp][wb2] = Pn; \
    *(uint2*)&lrows[56 + rgrp][wb2] = Po; *(uint2*)&lrows[60 + rgrp][wb2] = Pp; }

#define GRP16(B, ACC, SH) { \
    unsigned q0_=lrows[(B)+ 0][idxw_], q1_=lrows[(B)+ 1][idxw_], \
             q2_=lrows[(B)+ 2][idxw_], q3_=lrows[(B)+ 3][idxw_], \
             q4_=lrows[(B)+ 4][idxw_], q5_=lrows[(B)+ 5][idxw_], \
             q6_=lrows[(B)+ 6][idxw_], q7_=lrows[(B)+ 7][idxw_], \
             q8_=lrows[(B)+ 8][idxw_], q9_=lrows[(B)+ 9][idxw_], \
             qa_=lrows[(B)+10][idxw_], qb_=lrows[(B)+11][idxw_], \
             qc_=lrows[(B)+12][idxw_], qd_=lrows[(B)+13][idxw_], \
             qe_=lrows[(B)+14][idxw_], qf_=lrows[(B)+15][idxw_]; \
    ACC |= (((q0_>>pb_)&1u)<<((SH)+ 0)) | (((q1_>>pb_)&1u)<<((SH)+ 1)) \
         | (((q2_>>pb_)&1u)<<((SH)+ 2)) | (((q3_>>pb_)&1u)<<((SH)+ 3)) \
         | (((q4_>>pb_)&1u)<<((SH)+ 4)) | (((q5_>>pb_)&1u)<<((SH)+ 5)) \
         | (((q6_>>pb_)&1u)<<((SH)+ 6)) | (((q7_>>pb_)&1u)<<((SH)+ 7)) \
         | (((q8_>>pb_)&1u)<<((SH)+ 8)) | (((q9_>>pb_)&1u)<<((SH)+ 9)) \
         | (((qa_>>pb_)&1u)<<((SH)+10)) | (((qb_>>pb_)&1u)<<((SH)+11)) \
         | (((qc_>>pb_)&1u)<<((SH)+12)) | (((qd_>>pb_)&1u)<<((SH)+13)) \
         | (((qe_>>pb_)&1u)<<((SH)+14)) | (((qf_>>pb_)&1u)<<((SH)+15)); }

#define TPROC(INFO, BOX, SC, baseexpr) { \
    int base_ = (baseexpr); \
    unsigned L_ = ((INFO)>>10)&7u; unsigned p_ = (INFO) & 1023u; \
    int idxw_ = (int)(p_ >> 5); unsigned pb_ = p_ & 31u; \
    unsigned long long lb0_=__ballot(L_==0u), lb1_=__ballot(L_==1u), \
                       lb2_=__ballot(L_==2u), lb3_=__ballot(L_==3u), lb4_=__ballot(L_==4u); \
    unsigned long long myLvl_ = (L_==0u)?lb0_:(L_==1u)?lb1_:(L_==2u)?lb2_:(L_==3u)?lb3_:lb4_; \
    unsigned sw_ = ((const unsigned*)lsup2)[L_*32u + (unsigned)idxw_]; \
    bool ok_ = ((((INFO)>>13)&1u)!=0u) && (base_ + lane < K_SEL) && (((sw_>>pb_)&1u)==0u); \
    unsigned long long cand_ = __ballot(ok_); \
    unsigned alo_ = 0u, ahi_ = 0u; \
    GRP16( 0, alo_,  0); GRP16(16, alo_, 16); \
    GRP16(32, ahi_,  0); GRP16(48, ahi_, 16); \
    unsigned long long cm_ = ((((unsigned long long)ahi_)<<32)|(unsigned long long)alo_) & myLvl_; \
    unsigned long long keptM_ = 0ull; \
    while (cand_){ \
      bool safe_ = (((cand_>>lane)&1ull)!=0ull) && ((cm_ & cand_)==0ull); \
      unsigned long long nk_ = __ballot(safe_); \
      keptM_ |= nk_; \
      bool dead_ = (((cand_>>lane)&1ull)!=0ull) && ((cm_ & nk_)!=0ull); \
      cand_ &= ~(nk_ | __ballot(dead_)); \
    } \
    if (((keptM_>>lane)&1ull)!=0ull){ \
      unsigned long long* ls2_ = &lsup2[L_*16u]; \
      const unsigned long long* row2_ = (const unsigned long long*)&lrows[lane][0]; \
      _Pragma("unroll") \
      for (int k_ = 0; k_ < 16; ++k_){ \
        unsigned pr_ = (unsigned)((k_ + (lane & 15)) & 15); \
        unsigned long long rw_ = row2_[pr_]; \
        if (rw_) atomicOr(&ls2_[pr_], rw_);   /* sparse: most pairs are zero */ \
      } \
    } \
    int pos_ = kept_total + (int)__popcll(keptM_ & ((1ull<<lane)-1ull)); \
    if ((((keptM_>>lane)&1ull)!=0ull) && pos_ < PRE){ \
      float* orow_ = outn + (size_t)pos_*5; \
      orow_[0]=(BOX).x; orow_[1]=(BOX).y; orow_[2]=(BOX).z; orow_[3]=(BOX).w; orow_[4]=(SC); \
    } \
    kept_total += (int)__popcll(keptM_); \
    asm volatile("s_waitcnt lgkmcnt(0)" ::: "memory"); \
  }

  infoC = rin[lane];
  SLOAD(infoC);                          // tile 0 rows -> regs, box -> boxP
  SWRITE();                              // tile 0 rows -> LDS
  float4 boxC = boxP; float scC = scP;
  infoN = rin[64 + lane];

  for (int t = 0; t < TILES; ++t){
    if (t+1 < TILES) SLOAD(infoN);       // issue next tile's loads (rows + box)
    asm volatile("s_waitcnt lgkmcnt(0)" ::: "memory");   // lrows writes visible
    TPROC(infoC, boxC, scC, t*64);
    if (kept_total >= PRE) break;
    if (t+1 < TILES){
      SWRITE();                          // waits next tile's loads (covered by TPROC)
      boxC = boxP; scC = scP;
      infoC = infoN;
      if (t+2 < TILES){
        int nx = (t+2)*64 + lane; if (nx > K_SEL-1) nx = K_SEL-1;
        infoN = rin[nx];
      }
    }
  }
#undef SLOAD
#undef SWRITE
#undef GRP16
#undef TPROC
}

// ---------------- fallback path (ws too small): round-3 kernels ----------------
__global__ __launch_bounds__(256) void k_sortimg(const unsigned long long* keys,
                                                 const float* d0,const float* d1,const float* d2,const float* d3,const float* d4,
                                                 const float* anchors,
                                                 float4* sbox, float* sskey, int* slvl){
  int n = blockIdx.x;
  __shared__ unsigned long long sk[8192];
  for (int i = threadIdx.x; i < 8192; i += 256)
    sk[i] = (i < K_SEL) ? keys[(size_t)n*K_SEL + i] : ~0ULL;
  __syncthreads();
  bitonic<8192>(sk);
  for (int r = threadIdx.x; r < K_SEL; r += 256){
    unsigned long long key = sk[r];
    int t = (int)(key & 0x7FFFFu);
    int lvl = (int)((key >> 19) & 7u);
    unsigned se = ~((unsigned)(key >> 22));
    const float* dl = sel5(lvl,d0,d1,d2,d3,d4);
    BoxV b = decode_box(lvl, t, n, dl, anchors);
    sbox[(size_t)n*K_SEL + r] = make_float4(b.x1,b.y1,b.x2,b.y2);
    sskey[(size_t)n*K_SEL + r] = s2f(se);
    slvl[(size_t)n*K_SEL + r] = lvl;
  }
}

__global__ __launch_bounds__(256) void k_nms(const float4* sbox, const float* sskey, const int* slvl, float* out){
  int n = blockIdx.x, tid = threadIdx.x;
  __shared__ float kx1[PRE], ky1[PRE], kx2[PRE], ky2[PRE], kar[PRE];
  __shared__ int klv[PRE];
  __shared__ int nv_s, flag_s;
  for (int i = tid; i < PRE*5; i += 256) out[(size_t)n*PRE*5 + i] = 0.0f;
  if (tid == 0){ nv_s = 0; flag_s = 0; }
  __syncthreads();
  int c = 0;
  for (int i = tid; i < K_SEL; i += 256)
    if (sskey[(size_t)n*K_SEL + i] != -INFINITY) ++c;
  atomicAdd(&nv_s, c);
  __syncthreads();
  int nvalid = nv_s;
  int kept = 0;
  for (int i = 0; i < nvalid; ++i){
    float4 b = sbox[(size_t)n*K_SEL + i];
    int lv = slvl[(size_t)n*K_SEL + i];
    float off = (float)lv * 1345.0f;
    float ox1 = __fadd_rn(b.x, off), oy1 = __fadd_rn(b.y, off);
    float ox2 = __fadd_rn(b.z, off), oy2 = __fadd_rn(b.w, off);
    float area = __fmul_rn(__fsub_rn(ox2,ox1), __fsub_rn(oy2,oy1));
    bool hit = false;
    for (int j = tid; j < kept; j += 256){
      if (klv[j] == lv){
        float ltx = fmaxf(kx1[j], ox1), lty = fmaxf(ky1[j], oy1);
        float rbx = fminf(kx2[j], ox2), rby = fminf(ky2[j], oy2);
        float w = fmaxf(__fsub_rn(rbx,ltx), 0.0f);
        float h = fmaxf(__fsub_rn(rby,lty), 0.0f);
        float inter = __fmul_rn(w,h);
        float uni = __fsub_rn(__fadd_rn(kar[j], area), inter);
        if (__fdiv_rn(inter,uni) > 0.7f) hit = true;
      }
    }
    if (hit) flag_s = 1;
    __syncthreads();
    int sup = flag_s;
    __syncthreads();
    if (!sup){
      if (tid == 0){
        kx1[kept]=ox1; ky1[kept]=oy1; kx2[kept]=ox2; ky2[kept]=oy2; kar[kept]=area; klv[kept]=lv;
        float* orow = out + (size_t)n*PRE*5 + (size_t)kept*5;
        orow[0]=b.x; orow[1]=b.y; orow[2]=b.z; orow[3]=b.w;
        orow[4]=sskey[(size_t)n*K_SEL + i];
      }
      ++kept;
    }
    if (tid == 0) flag_s = 0;
    __syncthreads();
    if (kept == PRE) break;
  }
}

extern "C" void kernel_launch(void* const* d_in, const int* in_sizes, int n_in,
                              void* d_out, int out_size, void* d_ws, size_t ws_size,
                              hipStream_t stream) {
  bool interleaved = (in_sizes[1] == 4*in_sizes[0]);
  const float* obj[5]; const float* dlt[5];
  for (int i = 0; i < 5; ++i){
    if (interleaved){ obj[i] = (const float*)d_in[2*i]; dlt[i] = (const float*)d_in[2*i+1]; }
    else            { obj[i] = (const float*)d_in[i];   dlt[i] = (const float*)d_in[5+i]; }
  }
  const float* anchors = (const float*)d_in[10];

  char* ws = (char*)d_ws;
  unsigned* hist            = (unsigned*)(ws);                     // 655360
  unsigned* cnt_gt          = (unsigned*)(ws + 655360);            // 160
  unsigned* cnt_eq          = (unsigned*)(ws + 655520);            // 160
  unsigned* thi             = (unsigned*)(ws + 655680);            // 160 -> counters end 655840
  unsigned long long* cand  = (unsigned long long*)(ws + 655840);  // 1310720 -> 1966560
  unsigned long long* keys  = (unsigned long long*)(ws + 1966560); // 320000 -> 2286560
  float4* lbox              = (float4*)(ws + 2286560);             // 640000 -> 2926560
  float4* lobox             = (float4*)(ws + 2926560);             // 640000 -> 3566560
  float* loarea             = (float*)(ws + 3566560);              // 160000 -> 3726560
  float* lskey              = (float*)(ws + 3726560);              // 160000 -> 3886560
  unsigned* rankinfo        = (unsigned*)(ws + 3886560);           // 160000 -> 4046560
  unsigned* lmat            = (unsigned*)(ws + 4046560);           // 5120000 -> 9166560
  float4* sbox              = (float4*)(ws + 9166560);             // fallback: 640000 -> 9806560
  float* sskey              = (float*)(ws + 9806560);              // 160000 -> 9966560
  int* slvl                 = (int*)(ws + 9966560);                // 160000 -> 10126560
  const size_t NEED = 10126560;

  hipMemsetAsync(ws, 0, 655840, stream);   // hist + counters

  dim3 gChunk(42, 40);                   // 42 chunks x 8192 covers level-0's 338688
  k_hist<<<gChunk, 256, 0, stream>>>(obj[0],obj[1],obj[2],obj[3],obj[4], hist);
  k_scan<<<40, 256, 0, stream>>>(hist, thi);
  k_compact<<<gChunk, 256, 0, stream>>>(obj[0],obj[1],obj[2],obj[3],obj[4],
                                        dlt[0],dlt[1],dlt[2],dlt[3],dlt[4],
                                        anchors, thi, cnt_gt, cnt_eq, cand, keys);
  k_tiesel<<<dim3(16, 40), 256, 0, stream>>>(dlt[0],dlt[1],dlt[2],dlt[3],dlt[4], anchors,
                                             cnt_gt, cnt_eq, cand, keys);
  if (ws_size >= NEED){
    k_sortlvl<<<40, 256, 0, stream>>>(keys);
    k_declvl<<<dim3(8, 40), 256, 0, stream>>>(keys, dlt[0],dlt[1],dlt[2],dlt[3],dlt[4], anchors,
                                              lbox, lobox, loarea, lskey);
    k_rank<<<200, 256, 0, stream>>>(keys, rankinfo);
    k_ioumat_lvl<<<dim3(128, 40), 64, 0, stream>>>(lobox, loarea, lmat);
    k_scan_nms5<<<8, 64, 0, stream>>>(rankinfo, lmat, lbox, lskey, (float*)d_out);
  } else {
    k_sortimg<<<8, 256, 0, stream>>>(keys, dlt[0],dlt[1],dlt[2],dlt[3],dlt[4], anchors,
                                     sbox, sskey, slvl);
    k_nms<<<8, 256, 0, stream>>>(sbox, sskey, slvl, (float*)d_out);
  }
}